// Round 14
// baseline (229.151 us; speedup 1.0000x reference)
//
#include <hip/hip_runtime.h>

#define NN 100000
#define NE 200000
#define NG 5000
#define EPSI 1e-5f
#define NBLK 98   // ceil(NN/1024)

using short8 = __attribute__((ext_vector_type(8))) short;
using f32x4  = __attribute__((ext_vector_type(4))) float;

static __device__ inline short bfbits(float f) {
    __bf16 b = (__bf16)f;
    return __builtin_bit_cast(short, b);
}
static __device__ inline float bf2f(short s) {
    unsigned u = ((unsigned)(unsigned short)s) << 16;
    return __builtin_bit_cast(float, u);
}

// ===================== FAST-PATH workspace layout (floats) =====================
constexpr long FZ_NRM  = 0;                         // NN floats (src deg -> norm)
constexpr long FZ_STAT = NN;                        // 512 floats
constexpr long FZ_DCNT = NN + 512;                  // NN ints (dst count)
constexpr long ZN_FAST = 2L * NN + 512;             // zeroed region (~0.8 MB)
constexpr long O_OFFS  = ZN_FAST;                   // NN int
constexpr long O_CURS  = O_OFFS + NN;               // NN int
constexpr long O_PERM  = O_CURS + NN;               // NE int (dst-sorted edge ids)
constexpr long O_GLO   = O_PERM + NE;               // NG+1 int
constexpr long O_BSUM  = O_GLO + NG + 1;            // 256 int
constexpr long O_POOL  = ((O_BSUM + 256 + 3) & ~3L);// 64*NG float (16B-aligned)
constexpr long O_H1    = O_POOL + 64L * NG;         // 32*NN float
constexpr long O_OUT2  = O_H1 + 32L * NN;           // 64*NN float (also msg1 bf16, disjoint)
constexpr long O_MSG2  = O_OUT2 + 64L * NN;         // msg2 bf16 (32*NE floats worth) / fc1out
constexpr long O_H1B   = O_MSG2 + 32L * NE;         // h1b bf16 (16*NN floats worth)
constexpr long TOTAL_FAST = O_MSG2 + 64L * NE;      // ~23.33M floats = 93.3 MB

// ===================== FALLBACK workspace layout (floats) ======================
constexpr long B_NORM = 0;
constexpr long B_AGG1 = NN;
constexpr long B_AGG2 = B_AGG1 + 32L * NN;
constexpr long B_GSUM = B_AGG2 + 64L * NN;
constexpr long B_GCNT = B_GSUM + 64L * NG;
constexpr long B_STAT = B_GCNT + NG;
constexpr long ZERO_FB = B_STAT + 512;

// ===================== shared kernels =====================

__global__ void k_norm(float* __restrict__ deg) {
    int n = blockIdx.x * blockDim.x + threadIdx.x;
    if (n < NN) { float d = deg[n]; deg[n] = d > 0.f ? 1.f / d : 0.f; }
}

// ---------------------------------------------------------------------------
// Edge messages via MFMA. Groups of 32 edges; T14 async-STAGE split (ei 2
// groups ahead, data 1 group ahead; vmcnt wait after compute). HB: h input
// is BF16 (BN pre-applied). msg stored BF16 in edge order (coalesced).
// ---------------------------------------------------------------------------
template <int CI, int COLS, bool HB>
__global__ void __launch_bounds__(64 * (COLS / 16))
k_edge_lds(const int* __restrict__ ei, const float* __restrict__ ea,
           const void* __restrict__ hraw, const float* __restrict__ W,
           const float* __restrict__ nrm, unsigned short* __restrict__ msg)
{
    constexpr int KS = CI / 4;
    constexpr int TILES = COLS / 16;
    constexpr int BT = 64 * TILES;
    constexpr int HP  = 20;               // f32 pitch (CI=16 path)
    constexpr int HPB = 36;               // bf16 pitch (CI=32 path)
    constexpr int NGRP = NE / 32;         // 6250
    constexpr int TPR = BT / 32;
    constexpr int EPT = 256 / BT;
    constexpr int HBYTES = HB ? (32 * HPB * 2) : (32 * HP * 4);

    const int tid  = threadIdx.x;
    const int lane = tid & 63;
    const int wid  = tid >> 6;
    const int c = lane & 15;
    const int q = lane >> 4;

    short8 bfr[KS];
    {
        const float* wrow = W + (wid * 16 + c) * (CI * 8) + q * 8;
        #pragma unroll
        for (int kk = 0; kk < KS; ++kk) {
            const float* p = wrow + kk * 32;
            #pragma unroll
            for (int j = 0; j < 8; ++j) bfr[kk][j] = bfbits(p[j]);
        }
    }

    __shared__ __align__(16) unsigned char h_raw[2][HBYTES];
    __shared__ float ea_lds[2][32 * 9];

    const int hrow = tid / TPR;           // 0..31
    const int hj0  = (tid % TPR) * 4;     // 4-elem chunk
    const int erow = tid >> 3;
    const int ef   = tid & 7;

    auto writebuf = [&](int buf, float4 hv, ushort4 hu, float ev0, float ev1) {
        if constexpr (HB) {
            *reinterpret_cast<ushort4*>(
                (unsigned short*)h_raw[buf] + hrow * HPB + hj0) = hu;
        } else {
            *reinterpret_cast<float4*>(
                (float*)h_raw[buf] + hrow * HP + hj0) = hv;
        }
        ea_lds[buf][erow * 9 + ef] = ev0;
        if constexpr (EPT == 2) ea_lds[buf][(erow + 16) * 9 + ef] = ev1;
    };

    auto compute = [&](int buf, long e0) {
        #pragma unroll
        for (int et = 0; et < 2; ++et) {
            const int r = et * 16 + c;
            float ev[8];
            #pragma unroll
            for (int j = 0; j < 8; ++j) ev[j] = ea_lds[buf][r * 9 + j];
            f32x4 acc = {0.f, 0.f, 0.f, 0.f};
            #pragma unroll
            for (int kk = 0; kk < KS; ++kk) {
                float hv;
                if constexpr (HB)
                    hv = bf2f((short)((const unsigned short*)h_raw[buf])[r * HPB + kk * 4 + q]);
                else
                    hv = ((const float*)h_raw[buf])[r * HP + kk * 4 + q];
                short8 afr;
                #pragma unroll
                for (int j = 0; j < 8; ++j) afr[j] = bfbits(hv * ev[j]);
                acc = __builtin_amdgcn_mfma_f32_16x16x32_bf16(afr, bfr[kk], acc, 0, 0, 0);
            }
            #pragma unroll
            for (int t = 0; t < 4; ++t) {
                msg[(e0 + et * 16 + q * 4 + t) * COLS + wid * 16 + c] =
                    (unsigned short)bfbits(acc[t]);
            }
        }
    };

    const int GD = gridDim.x;
    int g = blockIdx.x;
    if (g >= NGRP) return;

    // ---- prologue ----
    int sh_c = ei[(long)g * 32 + hrow];
    int se0_c = ei[(long)g * 32 + erow];
    int se1_c = 0;
    if constexpr (EPT == 2) se1_c = ei[(long)g * 32 + erow + 16];
    int sh_n = 0, se0_n = 0, se1_n = 0;
    {
        int gn0 = g + GD;
        if (gn0 < NGRP) {
            sh_n = ei[(long)gn0 * 32 + hrow];
            se0_n = ei[(long)gn0 * 32 + erow];
            if constexpr (EPT == 2) se1_n = ei[(long)gn0 * 32 + erow + 16];
        }
    }
    float4 hv4 = {0.f, 0.f, 0.f, 0.f};
    ushort4 hu4 = {0, 0, 0, 0};
    float ev0 = 0.f, ev1 = 0.f;
    {
        if constexpr (HB)
            hu4 = *reinterpret_cast<const ushort4*>(
                (const unsigned short*)hraw + (long)sh_c * CI + hj0);
        else
            hv4 = *reinterpret_cast<const float4*>(
                (const float*)hraw + (long)sh_c * CI + hj0);
        ev0 = ea[((long)g * 32 + erow) * 8 + ef] * nrm[se0_c];
        if constexpr (EPT == 2)
            ev1 = ea[((long)g * 32 + erow + 16) * 8 + ef] * nrm[se1_c];
    }
    writebuf(0, hv4, hu4, ev0, ev1);
    __syncthreads();

    int p = 0;
    for (;;) {
        int gn = g + GD;
        bool more = (gn < NGRP);
        int gnn = gn + GD;
        int sh_f = 0, se0_f = 0, se1_f = 0;
        if (gnn < NGRP) {
            sh_f = ei[(long)gnn * 32 + hrow];
            se0_f = ei[(long)gnn * 32 + erow];
            if constexpr (EPT == 2) se1_f = ei[(long)gnn * 32 + erow + 16];
        }
        if (more) {
            if constexpr (HB)
                hu4 = *reinterpret_cast<const ushort4*>(
                    (const unsigned short*)hraw + (long)sh_n * CI + hj0);
            else
                hv4 = *reinterpret_cast<const float4*>(
                    (const float*)hraw + (long)sh_n * CI + hj0);
            ev0 = ea[((long)gn * 32 + erow) * 8 + ef] * nrm[se0_n];
            if constexpr (EPT == 2)
                ev1 = ea[((long)gn * 32 + erow + 16) * 8 + ef] * nrm[se1_n];
        }
        compute(p, (long)g * 32);
        if (!more) break;
        writebuf(p ^ 1, hv4, hu4, ev0, ev1);
        __syncthreads();
        sh_n = sh_f; se0_n = se0_f; se1_n = se1_f;
        g = gn; p ^= 1;
    }
}

// Fallback atomic-scatter MFMA edge kernel
template <int KS, int COLS>
__global__ void __launch_bounds__(256) k_edge_mfma_at(
    const int* __restrict__ ei, const float* __restrict__ ea,
    const float* __restrict__ h, const float* __restrict__ W,
    const float* __restrict__ nrm, float* __restrict__ outp)
{
    constexpr int TILES = COLS / 16;
    constexpr int CI = KS * 4;
    const int lane = threadIdx.x & 63;
    const int wid  = threadIdx.x >> 6;
    const int c = lane & 15;
    const int q = lane >> 4;
    const int gw = blockIdx.x * 4 + wid;
    const int ntile = gw % TILES;
    const int grp   = gw / TILES;
    if (grp >= NE / 16) return;
    short8 bfr[KS];
    {
        const float* wrow = W + (ntile * 16 + c) * (KS * 32) + q * 8;
        #pragma unroll
        for (int kk = 0; kk < KS; ++kk) {
            const float* p = wrow + kk * 32;
            #pragma unroll
            for (int j = 0; j < 8; ++j) bfr[kk][j] = bfbits(p[j]);
        }
    }
    const long e0 = (long)grp * 16;
    const long e  = e0 + c;
    const int  s  = ei[e];
    const float nv = nrm[s];
    float ev[8];
    {
        const float* p = ea + e * 8;
        #pragma unroll
        for (int j = 0; j < 8; ++j) ev[j] = p[j];
    }
    float hv[KS];
    {
        const float* hp = h + (long)s * CI + q;
        #pragma unroll
        for (int kk = 0; kk < KS; ++kk) hv[kk] = hp[kk * 4] * nv;
    }
    f32x4 acc = {0.f, 0.f, 0.f, 0.f};
    #pragma unroll
    for (int kk = 0; kk < KS; ++kk) {
        short8 afr;
        #pragma unroll
        for (int j = 0; j < 8; ++j) afr[j] = bfbits(hv[kk] * ev[j]);
        acc = __builtin_amdgcn_mfma_f32_16x16x32_bf16(afr, bfr[kk], acc, 0, 0, 0);
    }
    #pragma unroll
    for (int t = 0; t < 4; ++t) {
        int m = q * 4 + t;
        int d = ei[NE + e0 + m];
        atomicAdd(&outp[(long)d * COLS + ntile * 16 + c], acc[t]);
    }
}

template <int C>
__global__ void k_colstats(const float* __restrict__ v, float* __restrict__ sum,
                           float* __restrict__ ssq) {
    constexpr int RPB = 256 / C;
    const int c = threadIdx.x % C;
    const int r = threadIdx.x / C;
    float s = 0.f, q = 0.f;
    for (int n = blockIdx.x * RPB + r; n < NN; n += gridDim.x * RPB) {
        float val = v[(long)n * C + c];
        s += val; q += val * val;
    }
    __shared__ float ls[256], lq[256];
    ls[threadIdx.x] = s; lq[threadIdx.x] = q;
    __syncthreads();
    if (threadIdx.x < C) {
        float ts = 0.f, tq = 0.f;
        #pragma unroll
        for (int k = 0; k < RPB; ++k) { ts += ls[c + k * C]; tq += lq[c + k * C]; }
        atomicAdd(&sum[c], ts);
        atomicAdd(&ssq[c], tq);
    }
}

__global__ void k_fin(int C, const float* __restrict__ sum, const float* __restrict__ ssq,
                      const float* __restrict__ g, const float* __restrict__ be,
                      float* __restrict__ scale, float* __restrict__ shift) {
    int c = threadIdx.x;
    if (c < C) {
        float mu  = sum[c] / (float)NN;
        float var = ssq[c] / (float)NN - mu * mu;
        float rs  = rsqrtf(var + EPSI);
        float sc  = rs * g[c];
        scale[c] = sc;
        shift[c] = be[c] - mu * sc;
    }
}

__global__ void k_bnrelu32(const float* __restrict__ in, const float* __restrict__ scale,
                           const float* __restrict__ shift, float* __restrict__ outp) {
    long t = (long)blockIdx.x * blockDim.x + threadIdx.x;
    if (t < 32L * NN) {
        int c = (int)(t & 31);
        float v = in[t] * scale[c] + shift[c];
        outp[t] = v > 0.f ? v : 0.f;
    }
}

// h1 (f32) -> h1b (bf16) with BN+relu applied. 8 elems/thread, vectorized.
__global__ void __launch_bounds__(256) k_h1b(
    const float* __restrict__ h1, const float* __restrict__ scale,
    const float* __restrict__ shift, unsigned short* __restrict__ h1b)
{
    long t = (long)blockIdx.x * 256 + threadIdx.x;
    long base = t * 8;
    if (base >= 32L * NN) return;
    int c0 = (int)(base & 31);
    short8 outv;
    const float* p = h1 + base;
    #pragma unroll
    for (int j = 0; j < 8; ++j) {
        float v = fmaxf(fmaf(p[j], scale[c0 + j], shift[c0 + j]), 0.f);
        outv[j] = bfbits(v);
    }
    *reinterpret_cast<short8*>(h1b + base) = outv;
}

// ---------------------------------------------------------------------------
// FUSED root + message aggregation: Y[r,o] = (X @ W.T)[r,o] + bias[o]
//                                           + sum_{e: dst=r} msg[e,o]
// MFMA computes the root GEMM; each lane then gathers its 4 output rows'
// messages (perm broadcast within 16-lane group; msg reads 32B-contiguous).
// Single write of Y + in-register column stats. XB: X is BF16 -> 1 MFMA.
// ---------------------------------------------------------------------------
template <int CI, int CO, bool XB>
__global__ void __launch_bounds__(256) k_rootm(
    const void* __restrict__ Xraw, const float* __restrict__ W,
    const float* __restrict__ bias,
    const unsigned short* __restrict__ msg, const int* __restrict__ offs,
    const int* __restrict__ dcnt, const int* __restrict__ perm,
    float* __restrict__ Y, float* __restrict__ sum, float* __restrict__ ssq)
{
    constexpr int TILES = CO / 16;        // 4 (CO=64) or 2 (CO=32)
    constexpr int MT = NN / 16;           // 6250
    constexpr int MTPB = 4 / TILES;
    const int lane = threadIdx.x & 63;
    const int wid  = threadIdx.x >> 6;
    const int c = lane & 15;
    const int q = lane >> 4;
    const int ntile = (TILES == 4) ? wid : (wid & (TILES - 1));
    const int mtoff = (TILES == 4) ? 0 : (wid >> 1);
    const int o = ntile * 16 + c;
    const bool kvalid = (q * 8) < CI;

    short8 bhi = {0,0,0,0,0,0,0,0}, blo = {0,0,0,0,0,0,0,0};
    if (kvalid) {
        const float* wrow = W + (long)o * CI + q * 8;
        #pragma unroll
        for (int j = 0; j < 8; ++j) {
            float v = wrow[j];
            short h = bfbits(v);
            bhi[j] = h;
            blo[j] = bfbits(v - bf2f(h));
        }
    }
    const float bv = bias[o];
    float s_acc = 0.f, q_acc = 0.f;

    for (int mt = blockIdx.x * MTPB + mtoff; mt < MT; mt += gridDim.x * MTPB) {
        // node index bookkeeping for this tile (4 rows per lane)
        int lo[4], ct[4];
        #pragma unroll
        for (int t4 = 0; t4 < 4; ++t4) {
            int r = mt * 16 + q * 4 + t4;
            lo[t4] = offs[r];
            ct[t4] = dcnt[r];
        }
        // root GEMM
        f32x4 acc = {0.f, 0.f, 0.f, 0.f};
        if constexpr (XB) {
            short8 ahi = {0,0,0,0,0,0,0,0};
            if (kvalid)
                ahi = *reinterpret_cast<const short8*>(
                    (const unsigned short*)Xraw + (long)(mt * 16 + c) * CI + q * 8);
            acc = __builtin_amdgcn_mfma_f32_16x16x32_bf16(ahi, bhi, acc, 0, 0, 0);
        } else {
            short8 ahi = {0,0,0,0,0,0,0,0}, alo = {0,0,0,0,0,0,0,0};
            if (kvalid) {
                const float* xp = (const float*)Xraw + (long)(mt * 16 + c) * CI + q * 8;
                #pragma unroll
                for (int j = 0; j < 8; ++j) {
                    float v = xp[j];
                    short h = bfbits(v);
                    ahi[j] = h;
                    alo[j] = bfbits(v - bf2f(h));
                }
            }
            acc = __builtin_amdgcn_mfma_f32_16x16x32_bf16(ahi, bhi, acc, 0, 0, 0);
            acc = __builtin_amdgcn_mfma_f32_16x16x32_bf16(ahi, blo, acc, 0, 0, 0);
            acc = __builtin_amdgcn_mfma_f32_16x16x32_bf16(alo, bhi, acc, 0, 0, 0);
        }
        // message gather for this lane's 4 rows (col o)
        float ms[4];
        #pragma unroll
        for (int t4 = 0; t4 < 4; ++t4) {
            float a = 0.f, b = 0.f;
            int j = 0;
            for (; j + 1 < ct[t4]; j += 2) {
                int ep0 = perm[lo[t4] + j];
                int ep1 = perm[lo[t4] + j + 1];
                a += bf2f((short)msg[(long)ep0 * CO + o]);
                b += bf2f((short)msg[(long)ep1 * CO + o]);
            }
            if (j < ct[t4]) {
                int ep0 = perm[lo[t4] + j];
                a += bf2f((short)msg[(long)ep0 * CO + o]);
            }
            ms[t4] = a + b;
        }
        #pragma unroll
        for (int t4 = 0; t4 < 4; ++t4) {
            long r = (long)mt * 16 + q * 4 + t4;
            float v = acc[t4] + ms[t4] + bv;
            Y[r * CO + o] = v;
            s_acc += v;
            q_acc = fmaf(v, v, q_acc);
        }
    }

    __shared__ float ls[256], lq[256];
    ls[threadIdx.x] = s_acc; lq[threadIdx.x] = q_acc;
    __syncthreads();
    if (threadIdx.x < CO) {
        int ch = threadIdx.x;
        int bw = ch >> 4;
        int cc = ch & 15;
        float ts = 0.f, tq = 0.f;
        if (TILES == 4) {
            #pragma unroll
            for (int q2 = 0; q2 < 4; ++q2) {
                ts += ls[bw * 64 + q2 * 16 + cc];
                tq += lq[bw * 64 + q2 * 16 + cc];
            }
        } else {
            #pragma unroll
            for (int w2 = 0; w2 < 2; ++w2) {
                int w = bw + w2 * 2;
                #pragma unroll
                for (int q2 = 0; q2 < 4; ++q2) {
                    ts += ls[w * 64 + q2 * 16 + cc];
                    tq += lq[w * 64 + q2 * 16 + cc];
                }
            }
        }
        atomicAdd(&sum[ch], ts);
        atomicAdd(&ssq[ch], tq);
    }
}

// ---------------------------------------------------------------------------
// FC via MFMA with split-bf16 (hi/lo) for fp32-level accuracy.
// ---------------------------------------------------------------------------
template <int K, int NO, bool RELU, bool SPLITOUT>
__global__ void __launch_bounds__(256) k_fcmm(
    const float* __restrict__ X, const float* __restrict__ W,
    const float* __restrict__ bias, float* __restrict__ Y)
{
    constexpr int KS = K / 32;
    constexpr int TILES = NO / 16;
    constexpr int MT = (NG + 15) / 16;
    const int lane = threadIdx.x & 63;
    const int wid  = threadIdx.x >> 6;
    const int c = lane & 15;
    const int q = lane >> 4;
    const int gw = blockIdx.x * 4 + wid;
    const int ntile = gw % TILES;
    const int mt    = gw / TILES;
    if (mt >= MT) return;

    short8 bhi[KS], blo[KS];
    {
        const float* wrow = W + (ntile * 16 + c) * K + q * 8;
        #pragma unroll
        for (int kk = 0; kk < KS; ++kk) {
            const float* p = wrow + kk * 32;
            #pragma unroll
            for (int j = 0; j < 8; ++j) {
                float v = p[j];
                short h = bfbits(v);
                bhi[kk][j] = h;
                blo[kk][j] = bfbits(v - bf2f(h));
            }
        }
    }

    int arow = mt * 16 + c;
    if (arow > NG - 1) arow = NG - 1;
    const float* xp = X + (long)arow * K + q * 8;

    f32x4 acc = {0.f, 0.f, 0.f, 0.f};
    #pragma unroll
    for (int kk = 0; kk < KS; ++kk) {
        const float* p = xp + kk * 32;
        short8 ahi, alo;
        #pragma unroll
        for (int j = 0; j < 8; ++j) {
            float v = p[j];
            short h = bfbits(v);
            ahi[j] = h;
            alo[j] = bfbits(v - bf2f(h));
        }
        acc = __builtin_amdgcn_mfma_f32_16x16x32_bf16(ahi, bhi[kk], acc, 0, 0, 0);
        acc = __builtin_amdgcn_mfma_f32_16x16x32_bf16(ahi, blo[kk], acc, 0, 0, 0);
        acc = __builtin_amdgcn_mfma_f32_16x16x32_bf16(alo, bhi[kk], acc, 0, 0, 0);
    }

    const int o = ntile * 16 + c;
    const float bv = bias[o];
    #pragma unroll
    for (int t = 0; t < 4; ++t) {
        int r = mt * 16 + q * 4 + t;
        if (r < NG) {
            float v = acc[t] + bv;
            if (RELU) v = v > 0.f ? v : 0.f;
            if (SPLITOUT) {
                if (o < 64) Y[(long)r * 64 + o] = v;
                else        Y[(long)NG * 64 + (long)r * 64 + (o - 64)] = v;
            } else {
                Y[(long)r * NO + o] = v;
            }
        }
    }
}

// Old shuffle-based FC (fallback path only)
__global__ void k_fc(const float* __restrict__ pooled,
                     const float* __restrict__ Wf1, const float* __restrict__ bf1,
                     const float* __restrict__ Wf2, const float* __restrict__ bf2,
                     float* __restrict__ outp) {
    const int lane = threadIdx.x & 63;
    int gw = (blockIdx.x * blockDim.x + threadIdx.x) >> 6;
    int nw = (gridDim.x * blockDim.x) >> 6;
    for (int g = gw; g < NG; g += nw) {
        float pl = pooled[(long)g * 64 + lane];
        float f1a = bf1[lane], f1b = bf1[lane + 64];
        const float* w1a = Wf1 + lane * 64;
        const float* w1b = Wf1 + (lane + 64) * 64;
        #pragma unroll 8
        for (int i = 0; i < 64; ++i) {
            float pv = __shfl(pl, i);
            f1a += pv * w1a[i];
            f1b += pv * w1b[i];
        }
        f1a = f1a > 0.f ? f1a : 0.f;
        f1b = f1b > 0.f ? f1b : 0.f;
        float oa = bf2[lane], ob = bf2[lane + 64];
        const float* w2a = Wf2 + lane * 128;
        const float* w2b = Wf2 + (lane + 64) * 128;
        #pragma unroll 8
        for (int i = 0; i < 64; ++i) {
            float va = __shfl(f1a, i);
            float vb = __shfl(f1b, i);
            oa += va * w2a[i] + vb * w2a[64 + i];
            ob += va * w2b[i] + vb * w2b[64 + i];
        }
        outp[(long)g * 64 + lane] = oa;
        outp[(long)NG * 64 + (long)g * 64 + lane] = ob;
    }
}

// ===================== fast-path kernels =====================

__global__ void k_degcnt(const int* __restrict__ ei, float* __restrict__ deg,
                         int* __restrict__ dcnt) {
    int e = blockIdx.x * blockDim.x + threadIdx.x;
    if (e < NE) {
        atomicAdd(&deg[ei[e]], 1.0f);
        atomicAdd(&dcnt[ei[NE + e]], 1);
    }
}

// scanA + fused norm (deg -> 1/deg)
__global__ void k_scanA(const int* __restrict__ dcnt, int* __restrict__ offs,
                        int* __restrict__ bsum, float* __restrict__ deg) {
    int tid = threadIdx.x, b = blockIdx.x;
    int base = b * 1024 + tid * 4;
    int v[4]; int t = 0;
    #pragma unroll
    for (int k = 0; k < 4; ++k) { v[k] = (base + k < NN) ? dcnt[base + k] : 0; t += v[k]; }
    #pragma unroll
    for (int k = 0; k < 4; ++k) {
        int i = base + k;
        if (i < NN) { float d = deg[i]; deg[i] = d > 0.f ? 1.f / d : 0.f; }
    }
    __shared__ int s[256];
    s[tid] = t;
    __syncthreads();
    for (int d = 1; d < 256; d <<= 1) {
        int x = (tid >= d) ? s[tid - d] : 0;
        __syncthreads();
        s[tid] += x;
        __syncthreads();
    }
    int excl = s[tid] - t;
    int o = excl;
    #pragma unroll
    for (int k = 0; k < 4; ++k) {
        if (base + k < NN) offs[base + k] = o;
        o += v[k];
    }
    if (tid == 255) bsum[b] = s[255];
}

__global__ void k_scanB(int* __restrict__ bsum) {
    int tid = threadIdx.x;
    __shared__ int s[128];
    int val = (tid < NBLK) ? bsum[tid] : 0;
    s[tid] = val;
    __syncthreads();
    for (int d = 1; d < 128; d <<= 1) {
        int x = (tid >= d) ? s[tid - d] : 0;
        __syncthreads();
        s[tid] += x;
        __syncthreads();
    }
    bsum[tid] = s[tid] - val;
}

__global__ void k_scanC(int* __restrict__ offs, int* __restrict__ curs,
                        const int* __restrict__ bsum) {
    int tid = threadIdx.x, b = blockIdx.x;
    int base = b * 1024 + tid * 4;
    int add = bsum[b];
    #pragma unroll
    for (int k = 0; k < 4; ++k) {
        int i = base + k;
        if (i < NN) { int o = offs[i] + add; offs[i] = o; curs[i] = o; }
    }
}

// perm[pos] = edge id (dst-sorted); fused glo binary search
__global__ void k_scatter(const int* __restrict__ ei, int* __restrict__ curs,
                          int* __restrict__ perm, const int* __restrict__ batch,
                          int* __restrict__ glo) {
    int e = blockIdx.x * blockDim.x + threadIdx.x;
    if (e < NE) {
        int d = ei[NE + e];
        int pos = atomicAdd(&curs[d], 1);
        perm[pos] = e;
    }
    if (e <= NG) {
        int lo = 0, hi = NN;
        while (lo < hi) { int m = (lo + hi) >> 1; if (batch[m] < e) lo = m + 1; else hi = m; }
        glo[e] = lo;
    }
}

__global__ void k_poolg(const float* __restrict__ out2, const int* __restrict__ glo,
                        const float* __restrict__ scale, const float* __restrict__ shift,
                        float* __restrict__ pooled) {
    const int lane = threadIdx.x & 63;
    int g = (blockIdx.x * blockDim.x + threadIdx.x) >> 6;
    if (g >= NG) return;
    int lo = glo[g], hi = glo[g + 1];
    float sc = scale[lane], sh = shift[lane];
    float acc = 0.f;
    for (int n = lo; n < hi; ++n) {
        float v = out2[(long)n * 64 + lane] * sc + sh;
        acc += v > 0.f ? v : 0.f;
    }
    float m = (float)(hi - lo);
    pooled[(long)g * 64 + lane] = acc / (m > 1.f ? m : 1.f);
}

// ===================== fallback-only kernels =====================

__global__ void k_deg(const int* __restrict__ ei, float* __restrict__ deg) {
    int e = blockIdx.x * blockDim.x + threadIdx.x;
    if (e < NE) atomicAdd(&deg[ei[e]], 1.0f);
}

template <int CI, int CO>
__global__ void k_nodeadd(const float* __restrict__ xin, const float* __restrict__ Wr,
                          const float* __restrict__ b, float* __restrict__ outp) {
    constexpr int NPW = 64 / CO;
    const int lane = threadIdx.x & 63;
    const int c = lane % CO;
    const int sub = lane / CO;
    float w[CI];
    #pragma unroll
    for (int i = 0; i < CI; ++i) w[i] = Wr[c * CI + i];
    float bias = b[c];
    int gw = (blockIdx.x * blockDim.x + threadIdx.x) >> 6;
    int nw = (gridDim.x * blockDim.x) >> 6;
    for (int n0 = gw * NPW; n0 < NN; n0 += nw * NPW) {
        int n = n0 + sub;
        if (n < NN) {
            const float* xp = xin + (long)n * CI;
            float acc = outp[(long)n * CO + c] + bias;
            #pragma unroll
            for (int i = 0; i < CI; ++i) acc += xp[i] * w[i];
            outp[(long)n * CO + c] = acc;
        }
    }
}

__global__ void k_pool_at(const float* __restrict__ out2, const int* __restrict__ batch,
                          const float* __restrict__ scale, const float* __restrict__ shift,
                          float* __restrict__ gsum) {
    long t = (long)blockIdx.x * blockDim.x + threadIdx.x;
    int c = (int)(t & 63);
    long n0 = (t >> 6) * 4;
    if (n0 >= NN) return;
    float sc = scale[c], sh = shift[c];
    float acc = 0.f;
    int gprev = batch[n0];
    #pragma unroll
    for (int k = 0; k < 4; ++k) {
        long n = n0 + k;
        if (n >= NN) break;
        int g = batch[n];
        float v = out2[n * 64 + c] * sc + sh;
        v = v > 0.f ? v : 0.f;
        if (g != gprev) {
            atomicAdd(&gsum[(long)gprev * 64 + c], acc);
            acc = 0.f; gprev = g;
        }
        acc += v;
    }
    atomicAdd(&gsum[(long)gprev * 64 + c], acc);
}

__global__ void k_cnt(const int* __restrict__ batch, float* __restrict__ gcnt) {
    int n = blockIdx.x * blockDim.x + threadIdx.x;
    if (n < NN) atomicAdd(&gcnt[batch[n]], 1.0f);
}

__global__ void k_div(float* __restrict__ gsum, const float* __restrict__ gcnt) {
    long t = (long)blockIdx.x * blockDim.x + threadIdx.x;
    if (t < 64L * NG) {
        float cnt = gcnt[t >> 6];
        gsum[t] = gsum[t] / (cnt > 1.f ? cnt : 1.f);
    }
}

// ===================== host =====================

extern "C" void kernel_launch(void* const* d_in, const int* in_sizes, int n_in,
                              void* d_out, int out_size, void* d_ws, size_t ws_size,
                              hipStream_t stream) {
    const float* x   = (const float*)d_in[0];
    const int*   ei  = (const int*)d_in[1];
    const float* ea  = (const float*)d_in[2];
    const int*   bat = (const int*)d_in[3];
    const float* We1 = (const float*)d_in[4];
    const float* b1  = (const float*)d_in[5];
    const float* Wr1 = (const float*)d_in[6];
    const float* g1  = (const float*)d_in[7];
    const float* be1 = (const float*)d_in[8];
    const float* We2 = (const float*)d_in[9];
    const float* b2  = (const float*)d_in[10];
    const float* Wr2 = (const float*)d_in[11];
    const float* g2  = (const float*)d_in[12];
    const float* be2 = (const float*)d_in[13];
    const float* Wf1 = (const float*)d_in[14];
    const float* bf1 = (const float*)d_in[15];
    const float* Wf2 = (const float*)d_in[16];
    const float* bf2 = (const float*)d_in[17];
    float* out = (float*)d_out;
    float* ws  = (float*)d_ws;
    int*   wsi = (int*)d_ws;

    if (ws_size >= (size_t)TOTAL_FAST * sizeof(float)) {
        float* nrm    = ws + FZ_NRM;
        float* st     = ws + FZ_STAT;
        int*   dcnt   = wsi + FZ_DCNT;
        int*   offs   = wsi + O_OFFS;
        int*   curs   = wsi + O_CURS;
        int*   perm   = wsi + O_PERM;
        int*   glo    = wsi + O_GLO;
        int*   bsum   = wsi + O_BSUM;
        float* pooled = ws + O_POOL;
        float* h1     = ws + O_H1;
        float* out2   = ws + O_OUT2;
        unsigned short* msg1 = (unsigned short*)(ws + O_OUT2);  // disjoint lifetime
        unsigned short* msg2 = (unsigned short*)(ws + O_MSG2);
        unsigned short* h1b  = (unsigned short*)(ws + O_H1B);
        float* fc1out = ws + O_MSG2;   // reuses msg2 region (dead after rootm2)
        float* sums1 = st;        float* ssq1 = st + 32;
        float* sums2 = st + 64;   float* ssq2 = st + 128;
        float* sc1   = st + 192;  float* sh1  = st + 224;
        float* sc2   = st + 256;  float* sh2  = st + 320;

        hipMemsetAsync(d_ws, 0, (size_t)ZN_FAST * sizeof(float), stream);

        k_degcnt<<<(NE + 255) / 256, 256, 0, stream>>>(ei, nrm, dcnt);
        k_scanA<<<NBLK, 256, 0, stream>>>(dcnt, offs, bsum, nrm);
        k_scanB<<<1, 128, 0, stream>>>(bsum);
        k_scanC<<<NBLK, 256, 0, stream>>>(offs, curs, bsum);
        k_scatter<<<(NE + 255) / 256, 256, 0, stream>>>(ei, curs, perm, bat, glo);

        // ---- layer 1 ----
        k_edge_lds<16, 32, false><<<2048, 128, 0, stream>>>(
            ei, ea, x, We1, nrm, msg1);
        k_rootm<16, 32, false><<<1024, 256, 0, stream>>>(
            x, Wr1, b1, msg1, offs, dcnt, perm, h1, sums1, ssq1);
        k_fin<<<1, 64, 0, stream>>>(32, sums1, ssq1, g1, be1, sc1, sh1);
        // h1 -> h1b (bf16, BN+relu folded)
        k_h1b<<<(int)((32L * NN / 8 + 255) / 256), 256, 0, stream>>>(h1, sc1, sh1, h1b);

        // ---- layer 2 (inputs pre-normalized bf16) ----
        k_edge_lds<32, 64, true><<<2048, 256, 0, stream>>>(
            ei, ea, h1b, We2, nrm, msg2);
        k_rootm<32, 64, true><<<1568, 256, 0, stream>>>(
            h1b, Wr2, b2, msg2, offs, dcnt, perm, out2, sums2, ssq2);
        k_fin<<<1, 64, 0, stream>>>(64, sums2, ssq2, g2, be2, sc2, sh2);

        k_poolg<<<1250, 256, 0, stream>>>(out2, glo, sc2, sh2, pooled);

        {
            constexpr int MT = (NG + 15) / 16;      // 313
            k_fcmm<64, 128, true,  false><<<(MT * 8 + 3) / 4, 256, 0, stream>>>(pooled, Wf1, bf1, fc1out);
            k_fcmm<128, 128, false, true><<<(MT * 8 + 3) / 4, 256, 0, stream>>>(fc1out, Wf2, bf2, out);
        }
    } else {
        float* nrm   = ws + B_NORM;
        float* agg1  = ws + B_AGG1;
        float* agg2  = ws + B_AGG2;
        float* gsum  = ws + B_GSUM;
        float* gcnt  = ws + B_GCNT;
        float* st    = ws + B_STAT;
        float* sums1 = st;        float* ssq1 = st + 32;
        float* sums2 = st + 64;   float* ssq2 = st + 128;
        float* sc1   = st + 192;  float* sh1  = st + 224;
        float* sc2   = st + 256;  float* sh2  = st + 320;

        hipMemsetAsync(d_ws, 0, (size_t)ZERO_FB * sizeof(float), stream);

        k_deg<<<(NE + 255) / 256, 256, 0, stream>>>(ei, nrm);
        k_norm<<<(NN + 255) / 256, 256, 0, stream>>>(nrm);

        k_edge_mfma_at<4, 32><<<6250, 256, 0, stream>>>(ei, ea, x, We1, nrm, agg1);
        k_nodeadd<16, 32><<<1024, 256, 0, stream>>>(x, Wr1, b1, agg1);
        k_colstats<32><<<1024, 256, 0, stream>>>(agg1, sums1, ssq1);
        k_fin<<<1, 64, 0, stream>>>(32, sums1, ssq1, g1, be1, sc1, sh1);
        k_bnrelu32<<<(int)((32L * NN + 255) / 256), 256, 0, stream>>>(agg1, sc1, sh1, agg1);

        k_edge_mfma_at<8, 64><<<12500, 256, 0, stream>>>(ei, ea, agg1, We2, nrm, agg2);
        k_nodeadd<32, 64><<<1024, 256, 0, stream>>>(agg1, Wr2, b2, agg2);
        k_colstats<64><<<1024, 256, 0, stream>>>(agg2, sums2, ssq2);
        k_fin<<<1, 64, 0, stream>>>(64, sums2, ssq2, g2, be2, sc2, sh2);

        k_pool_at<<<6250, 256, 0, stream>>>(agg2, bat, sc2, sh2, gsum);
        k_cnt<<<(NN + 255) / 256, 256, 0, stream>>>(bat, gcnt);
        k_div<<<(int)((64L * NG + 255) / 256), 256, 0, stream>>>(gsum, gcnt);
        k_fc<<<1250, 256, 0, stream>>>(gsum, Wf1, bf1, Wf2, bf2, out);
    }
}

// Round 15
// 190.654 us; speedup vs baseline: 1.2019x; 1.2019x over previous
//
#include <hip/hip_runtime.h>

#define NN 100000
#define NE 200000
#define NG 5000
#define EPSI 1e-5f
#define NBLK 98   // ceil(NN/1024)

using short8 = __attribute__((ext_vector_type(8))) short;
using f32x4  = __attribute__((ext_vector_type(4))) float;

static __device__ inline short bfbits(float f) {
    __bf16 b = (__bf16)f;
    return __builtin_bit_cast(short, b);
}
static __device__ inline float bf2f(short s) {
    unsigned u = ((unsigned)(unsigned short)s) << 16;
    return __builtin_bit_cast(float, u);
}

// ===================== FAST-PATH workspace layout (floats) =====================
constexpr long FZ_NRM  = 0;                         // NN floats (src deg -> norm)
constexpr long FZ_STAT = NN;                        // 512 floats
constexpr long FZ_DCNT = NN + 512;                  // NN ints (dst count)
constexpr long ZN_FAST = 2L * NN + 512;             // zeroed region (~0.8 MB)
constexpr long O_OFFS  = ZN_FAST;                   // NN int
constexpr long O_CURS  = O_OFFS + NN;               // NN int
constexpr long O_PERM  = O_CURS + NN;               // NE int (dst-sorted edge ids)
constexpr long O_GLO   = O_PERM + NE;               // NG+1 int
constexpr long O_BSUM  = O_GLO + NG + 1;            // 256 int
constexpr long O_POOL  = ((O_BSUM + 256 + 3) & ~3L);// 64*NG float (16B-aligned)
constexpr long O_H1    = O_POOL + 64L * NG;         // 32*NN float
constexpr long O_OUT2  = O_H1 + 32L * NN;           // 64*NN float (also msg1 bf16, disjoint)
constexpr long O_MSG2  = O_OUT2 + 64L * NN;         // msg2 bf16 (32*NE floats worth) / fc1out
constexpr long O_H1B   = O_MSG2 + 32L * NE;         // h1b bf16 (16*NN floats worth)
constexpr long TOTAL_FAST = O_MSG2 + 64L * NE;      // ~23.33M floats = 93.3 MB

// ===================== FALLBACK workspace layout (floats) ======================
constexpr long B_NORM = 0;
constexpr long B_AGG1 = NN;
constexpr long B_AGG2 = B_AGG1 + 32L * NN;
constexpr long B_GSUM = B_AGG2 + 64L * NN;
constexpr long B_GCNT = B_GSUM + 64L * NG;
constexpr long B_STAT = B_GCNT + NG;
constexpr long ZERO_FB = B_STAT + 512;

// ===================== shared kernels =====================

__global__ void k_norm(float* __restrict__ deg) {
    int n = blockIdx.x * blockDim.x + threadIdx.x;
    if (n < NN) { float d = deg[n]; deg[n] = d > 0.f ? 1.f / d : 0.f; }
}

// ---------------------------------------------------------------------------
// Edge messages via MFMA. Groups of 32 edges; T14 async-STAGE split (ei 2
// groups ahead, data 1 group ahead; vmcnt wait after compute). HB: h input
// is BF16 (BN pre-applied). msg stored BF16 in edge order (coalesced).
// ---------------------------------------------------------------------------
template <int CI, int COLS, bool HB>
__global__ void __launch_bounds__(64 * (COLS / 16))
k_edge_lds(const int* __restrict__ ei, const float* __restrict__ ea,
           const void* __restrict__ hraw, const float* __restrict__ W,
           const float* __restrict__ nrm, unsigned short* __restrict__ msg)
{
    constexpr int KS = CI / 4;
    constexpr int TILES = COLS / 16;
    constexpr int BT = 64 * TILES;
    constexpr int HP  = 20;               // f32 pitch (CI=16 path)
    constexpr int HPB = 36;               // bf16 pitch (CI=32 path)
    constexpr int NGRP = NE / 32;         // 6250
    constexpr int TPR = BT / 32;
    constexpr int EPT = 256 / BT;
    constexpr int HBYTES = HB ? (32 * HPB * 2) : (32 * HP * 4);

    const int tid  = threadIdx.x;
    const int lane = tid & 63;
    const int wid  = tid >> 6;
    const int c = lane & 15;
    const int q = lane >> 4;

    short8 bfr[KS];
    {
        const float* wrow = W + (wid * 16 + c) * (CI * 8) + q * 8;
        #pragma unroll
        for (int kk = 0; kk < KS; ++kk) {
            const float* p = wrow + kk * 32;
            #pragma unroll
            for (int j = 0; j < 8; ++j) bfr[kk][j] = bfbits(p[j]);
        }
    }

    __shared__ __align__(16) unsigned char h_raw[2][HBYTES];
    __shared__ float ea_lds[2][32 * 9];

    const int hrow = tid / TPR;           // 0..31
    const int hj0  = (tid % TPR) * 4;     // 4-elem chunk
    const int erow = tid >> 3;
    const int ef   = tid & 7;

    auto writebuf = [&](int buf, float4 hv, ushort4 hu, float ev0, float ev1) {
        if constexpr (HB) {
            *reinterpret_cast<ushort4*>(
                (unsigned short*)h_raw[buf] + hrow * HPB + hj0) = hu;
        } else {
            *reinterpret_cast<float4*>(
                (float*)h_raw[buf] + hrow * HP + hj0) = hv;
        }
        ea_lds[buf][erow * 9 + ef] = ev0;
        if constexpr (EPT == 2) ea_lds[buf][(erow + 16) * 9 + ef] = ev1;
    };

    auto compute = [&](int buf, long e0) {
        #pragma unroll
        for (int et = 0; et < 2; ++et) {
            const int r = et * 16 + c;
            float ev[8];
            #pragma unroll
            for (int j = 0; j < 8; ++j) ev[j] = ea_lds[buf][r * 9 + j];
            f32x4 acc = {0.f, 0.f, 0.f, 0.f};
            #pragma unroll
            for (int kk = 0; kk < KS; ++kk) {
                float hv;
                if constexpr (HB)
                    hv = bf2f((short)((const unsigned short*)h_raw[buf])[r * HPB + kk * 4 + q]);
                else
                    hv = ((const float*)h_raw[buf])[r * HP + kk * 4 + q];
                short8 afr;
                #pragma unroll
                for (int j = 0; j < 8; ++j) afr[j] = bfbits(hv * ev[j]);
                acc = __builtin_amdgcn_mfma_f32_16x16x32_bf16(afr, bfr[kk], acc, 0, 0, 0);
            }
            #pragma unroll
            for (int t = 0; t < 4; ++t) {
                msg[(e0 + et * 16 + q * 4 + t) * COLS + wid * 16 + c] =
                    (unsigned short)bfbits(acc[t]);
            }
        }
    };

    const int GD = gridDim.x;
    int g = blockIdx.x;
    if (g >= NGRP) return;

    // ---- prologue ----
    int sh_c = ei[(long)g * 32 + hrow];
    int se0_c = ei[(long)g * 32 + erow];
    int se1_c = 0;
    if constexpr (EPT == 2) se1_c = ei[(long)g * 32 + erow + 16];
    int sh_n = 0, se0_n = 0, se1_n = 0;
    {
        int gn0 = g + GD;
        if (gn0 < NGRP) {
            sh_n = ei[(long)gn0 * 32 + hrow];
            se0_n = ei[(long)gn0 * 32 + erow];
            if constexpr (EPT == 2) se1_n = ei[(long)gn0 * 32 + erow + 16];
        }
    }
    float4 hv4 = {0.f, 0.f, 0.f, 0.f};
    ushort4 hu4 = {0, 0, 0, 0};
    float ev0 = 0.f, ev1 = 0.f;
    {
        if constexpr (HB)
            hu4 = *reinterpret_cast<const ushort4*>(
                (const unsigned short*)hraw + (long)sh_c * CI + hj0);
        else
            hv4 = *reinterpret_cast<const float4*>(
                (const float*)hraw + (long)sh_c * CI + hj0);
        ev0 = ea[((long)g * 32 + erow) * 8 + ef] * nrm[se0_c];
        if constexpr (EPT == 2)
            ev1 = ea[((long)g * 32 + erow + 16) * 8 + ef] * nrm[se1_c];
    }
    writebuf(0, hv4, hu4, ev0, ev1);
    __syncthreads();

    int p = 0;
    for (;;) {
        int gn = g + GD;
        bool more = (gn < NGRP);
        int gnn = gn + GD;
        int sh_f = 0, se0_f = 0, se1_f = 0;
        if (gnn < NGRP) {
            sh_f = ei[(long)gnn * 32 + hrow];
            se0_f = ei[(long)gnn * 32 + erow];
            if constexpr (EPT == 2) se1_f = ei[(long)gnn * 32 + erow + 16];
        }
        if (more) {
            if constexpr (HB)
                hu4 = *reinterpret_cast<const ushort4*>(
                    (const unsigned short*)hraw + (long)sh_n * CI + hj0);
            else
                hv4 = *reinterpret_cast<const float4*>(
                    (const float*)hraw + (long)sh_n * CI + hj0);
            ev0 = ea[((long)gn * 32 + erow) * 8 + ef] * nrm[se0_n];
            if constexpr (EPT == 2)
                ev1 = ea[((long)gn * 32 + erow + 16) * 8 + ef] * nrm[se1_n];
        }
        compute(p, (long)g * 32);
        if (!more) break;
        writebuf(p ^ 1, hv4, hu4, ev0, ev1);
        __syncthreads();
        sh_n = sh_f; se0_n = se0_f; se1_n = se1_f;
        g = gn; p ^= 1;
    }
}

// Fallback atomic-scatter MFMA edge kernel
template <int KS, int COLS>
__global__ void __launch_bounds__(256) k_edge_mfma_at(
    const int* __restrict__ ei, const float* __restrict__ ea,
    const float* __restrict__ h, const float* __restrict__ W,
    const float* __restrict__ nrm, float* __restrict__ outp)
{
    constexpr int TILES = COLS / 16;
    constexpr int CI = KS * 4;
    const int lane = threadIdx.x & 63;
    const int wid  = threadIdx.x >> 6;
    const int c = lane & 15;
    const int q = lane >> 4;
    const int gw = blockIdx.x * 4 + wid;
    const int ntile = gw % TILES;
    const int grp   = gw / TILES;
    if (grp >= NE / 16) return;
    short8 bfr[KS];
    {
        const float* wrow = W + (ntile * 16 + c) * (KS * 32) + q * 8;
        #pragma unroll
        for (int kk = 0; kk < KS; ++kk) {
            const float* p = wrow + kk * 32;
            #pragma unroll
            for (int j = 0; j < 8; ++j) bfr[kk][j] = bfbits(p[j]);
        }
    }
    const long e0 = (long)grp * 16;
    const long e  = e0 + c;
    const int  s  = ei[e];
    const float nv = nrm[s];
    float ev[8];
    {
        const float* p = ea + e * 8;
        #pragma unroll
        for (int j = 0; j < 8; ++j) ev[j] = p[j];
    }
    float hv[KS];
    {
        const float* hp = h + (long)s * CI + q;
        #pragma unroll
        for (int kk = 0; kk < KS; ++kk) hv[kk] = hp[kk * 4] * nv;
    }
    f32x4 acc = {0.f, 0.f, 0.f, 0.f};
    #pragma unroll
    for (int kk = 0; kk < KS; ++kk) {
        short8 afr;
        #pragma unroll
        for (int j = 0; j < 8; ++j) afr[j] = bfbits(hv[kk] * ev[j]);
        acc = __builtin_amdgcn_mfma_f32_16x16x32_bf16(afr, bfr[kk], acc, 0, 0, 0);
    }
    #pragma unroll
    for (int t = 0; t < 4; ++t) {
        int m = q * 4 + t;
        int d = ei[NE + e0 + m];
        atomicAdd(&outp[(long)d * COLS + ntile * 16 + c], acc[t]);
    }
}

template <int C>
__global__ void k_colstats(const float* __restrict__ v, float* __restrict__ sum,
                           float* __restrict__ ssq) {
    constexpr int RPB = 256 / C;
    const int c = threadIdx.x % C;
    const int r = threadIdx.x / C;
    float s = 0.f, q = 0.f;
    for (int n = blockIdx.x * RPB + r; n < NN; n += gridDim.x * RPB) {
        float val = v[(long)n * C + c];
        s += val; q += val * val;
    }
    __shared__ float ls[256], lq[256];
    ls[threadIdx.x] = s; lq[threadIdx.x] = q;
    __syncthreads();
    if (threadIdx.x < C) {
        float ts = 0.f, tq = 0.f;
        #pragma unroll
        for (int k = 0; k < RPB; ++k) { ts += ls[c + k * C]; tq += lq[c + k * C]; }
        atomicAdd(&sum[c], ts);
        atomicAdd(&ssq[c], tq);
    }
}

__global__ void k_fin(int C, const float* __restrict__ sum, const float* __restrict__ ssq,
                      const float* __restrict__ g, const float* __restrict__ be,
                      float* __restrict__ scale, float* __restrict__ shift) {
    int c = threadIdx.x;
    if (c < C) {
        float mu  = sum[c] / (float)NN;
        float var = ssq[c] / (float)NN - mu * mu;
        float rs  = rsqrtf(var + EPSI);
        float sc  = rs * g[c];
        scale[c] = sc;
        shift[c] = be[c] - mu * sc;
    }
}

__global__ void k_bnrelu32(const float* __restrict__ in, const float* __restrict__ scale,
                           const float* __restrict__ shift, float* __restrict__ outp) {
    long t = (long)blockIdx.x * blockDim.x + threadIdx.x;
    if (t < 32L * NN) {
        int c = (int)(t & 31);
        float v = in[t] * scale[c] + shift[c];
        outp[t] = v > 0.f ? v : 0.f;
    }
}

// h1 (f32) -> h1b (bf16) with BN+relu applied. 8 elems/thread, vectorized.
__global__ void __launch_bounds__(256) k_h1b(
    const float* __restrict__ h1, const float* __restrict__ scale,
    const float* __restrict__ shift, unsigned short* __restrict__ h1b)
{
    long t = (long)blockIdx.x * 256 + threadIdx.x;
    long base = t * 8;
    if (base >= 32L * NN) return;
    int c0 = (int)(base & 31);
    short8 outv;
    const float* p = h1 + base;
    #pragma unroll
    for (int j = 0; j < 8; ++j) {
        float v = fmaxf(fmaf(p[j], scale[c0 + j], shift[c0 + j]), 0.f);
        outv[j] = bfbits(v);
    }
    *reinterpret_cast<short8*>(h1b + base) = outv;
}

// ---------------------------------------------------------------------------
// Segment-sum with perm gather over BF16 messages: thread = (node, 4-ch chunk).
// ---------------------------------------------------------------------------
template <int CO>
__global__ void __launch_bounds__(256) k_msum(
    const unsigned short* __restrict__ msg, const int* __restrict__ offs,
    const int* __restrict__ dcnt, const int* __restrict__ perm,
    float* __restrict__ aggout)
{
    constexpr int CPN = CO / 4;
    long t = (long)blockIdx.x * 256 + threadIdx.x;
    long n = t / CPN;
    int chunk = (int)(t % CPN);
    if (n >= NN) return;
    int lo = offs[n], ct = dcnt[n];
    f32x4 a = {0.f, 0.f, 0.f, 0.f}, b = {0.f, 0.f, 0.f, 0.f};
    int j = 0;
    for (; j + 1 < ct; j += 2) {
        int e0p = perm[lo + j];
        int e1p = perm[lo + j + 1];
        ushort4 u0 = *reinterpret_cast<const ushort4*>(msg + (long)e0p * CO + chunk * 4);
        ushort4 u1 = *reinterpret_cast<const ushort4*>(msg + (long)e1p * CO + chunk * 4);
        a.x += bf2f((short)u0.x); a.y += bf2f((short)u0.y);
        a.z += bf2f((short)u0.z); a.w += bf2f((short)u0.w);
        b.x += bf2f((short)u1.x); b.y += bf2f((short)u1.y);
        b.z += bf2f((short)u1.z); b.w += bf2f((short)u1.w);
    }
    if (j < ct) {
        int e0p = perm[lo + j];
        ushort4 u0 = *reinterpret_cast<const ushort4*>(msg + (long)e0p * CO + chunk * 4);
        a.x += bf2f((short)u0.x); a.y += bf2f((short)u0.y);
        a.z += bf2f((short)u0.z); a.w += bf2f((short)u0.w);
    }
    a += b;
    *reinterpret_cast<f32x4*>(aggout + n * CO + chunk * 4) = a;
}

// ---------------------------------------------------------------------------
// Root transform as streaming MFMA GEMM, fused: in-place add onto msum
// output + bias + column stats. XB: X is BF16 (BN pre-applied) -> 1 MFMA;
// else split-bf16 hi/lo (3 MFMAs) on f32 X.
// ---------------------------------------------------------------------------
template <int CI, int CO, bool XB>
__global__ void __launch_bounds__(256) k_root(
    const void* __restrict__ Xraw, const float* __restrict__ W,
    const float* __restrict__ bias, float* __restrict__ Y,
    float* __restrict__ sum, float* __restrict__ ssq)
{
    constexpr int TILES = CO / 16;        // 4 (CO=64) or 2 (CO=32)
    constexpr int MT = NN / 16;           // 6250
    constexpr int MTPB = 4 / TILES;
    const int lane = threadIdx.x & 63;
    const int wid  = threadIdx.x >> 6;
    const int c = lane & 15;
    const int q = lane >> 4;
    const int ntile = (TILES == 4) ? wid : (wid & (TILES - 1));
    const int mtoff = (TILES == 4) ? 0 : (wid >> 1);
    const int o = ntile * 16 + c;
    const bool kvalid = (q * 8) < CI;

    short8 bhi = {0,0,0,0,0,0,0,0}, blo = {0,0,0,0,0,0,0,0};
    if (kvalid) {
        const float* wrow = W + (long)o * CI + q * 8;
        #pragma unroll
        for (int j = 0; j < 8; ++j) {
            float v = wrow[j];
            short h = bfbits(v);
            bhi[j] = h;
            blo[j] = bfbits(v - bf2f(h));
        }
    }
    const float bv = bias[o];
    float s_acc = 0.f, q_acc = 0.f;

    for (int mt = blockIdx.x * MTPB + mtoff; mt < MT; mt += gridDim.x * MTPB) {
        f32x4 acc = {0.f, 0.f, 0.f, 0.f};
        if constexpr (XB) {
            short8 ahi = {0,0,0,0,0,0,0,0};
            if (kvalid)
                ahi = *reinterpret_cast<const short8*>(
                    (const unsigned short*)Xraw + (long)(mt * 16 + c) * CI + q * 8);
            acc = __builtin_amdgcn_mfma_f32_16x16x32_bf16(ahi, bhi, acc, 0, 0, 0);
        } else {
            short8 ahi = {0,0,0,0,0,0,0,0}, alo = {0,0,0,0,0,0,0,0};
            if (kvalid) {
                const float* xp = (const float*)Xraw + (long)(mt * 16 + c) * CI + q * 8;
                #pragma unroll
                for (int j = 0; j < 8; ++j) {
                    float v = xp[j];
                    short h = bfbits(v);
                    ahi[j] = h;
                    alo[j] = bfbits(v - bf2f(h));
                }
            }
            acc = __builtin_amdgcn_mfma_f32_16x16x32_bf16(ahi, bhi, acc, 0, 0, 0);
            acc = __builtin_amdgcn_mfma_f32_16x16x32_bf16(ahi, blo, acc, 0, 0, 0);
            acc = __builtin_amdgcn_mfma_f32_16x16x32_bf16(alo, bhi, acc, 0, 0, 0);
        }
        #pragma unroll
        for (int t4 = 0; t4 < 4; ++t4) {
            long r = (long)mt * 16 + q * 4 + t4;
            long idx = r * CO + o;
            float v = Y[idx] + acc[t4] + bv;
            Y[idx] = v;
            s_acc += v;
            q_acc = fmaf(v, v, q_acc);
        }
    }

    __shared__ float ls[256], lq[256];
    ls[threadIdx.x] = s_acc; lq[threadIdx.x] = q_acc;
    __syncthreads();
    if (threadIdx.x < CO) {
        int ch = threadIdx.x;
        int bw = ch >> 4;
        int cc = ch & 15;
        float ts = 0.f, tq = 0.f;
        if (TILES == 4) {
            #pragma unroll
            for (int q2 = 0; q2 < 4; ++q2) {
                ts += ls[bw * 64 + q2 * 16 + cc];
                tq += lq[bw * 64 + q2 * 16 + cc];
            }
        } else {
            #pragma unroll
            for (int w2 = 0; w2 < 2; ++w2) {
                int w = bw + w2 * 2;
                #pragma unroll
                for (int q2 = 0; q2 < 4; ++q2) {
                    ts += ls[w * 64 + q2 * 16 + cc];
                    tq += lq[w * 64 + q2 * 16 + cc];
                }
            }
        }
        atomicAdd(&sum[ch], ts);
        atomicAdd(&ssq[ch], tq);
    }
}

// ---------------------------------------------------------------------------
// FC via MFMA with split-bf16 (hi/lo) for fp32-level accuracy.
// ---------------------------------------------------------------------------
template <int K, int NO, bool RELU, bool SPLITOUT>
__global__ void __launch_bounds__(256) k_fcmm(
    const float* __restrict__ X, const float* __restrict__ W,
    const float* __restrict__ bias, float* __restrict__ Y)
{
    constexpr int KS = K / 32;
    constexpr int TILES = NO / 16;
    constexpr int MT = (NG + 15) / 16;
    const int lane = threadIdx.x & 63;
    const int wid  = threadIdx.x >> 6;
    const int c = lane & 15;
    const int q = lane >> 4;
    const int gw = blockIdx.x * 4 + wid;
    const int ntile = gw % TILES;
    const int mt    = gw / TILES;
    if (mt >= MT) return;

    short8 bhi[KS], blo[KS];
    {
        const float* wrow = W + (ntile * 16 + c) * K + q * 8;
        #pragma unroll
        for (int kk = 0; kk < KS; ++kk) {
            const float* p = wrow + kk * 32;
            #pragma unroll
            for (int j = 0; j < 8; ++j) {
                float v = p[j];
                short h = bfbits(v);
                bhi[kk][j] = h;
                blo[kk][j] = bfbits(v - bf2f(h));
            }
        }
    }

    int arow = mt * 16 + c;
    if (arow > NG - 1) arow = NG - 1;
    const float* xp = X + (long)arow * K + q * 8;

    f32x4 acc = {0.f, 0.f, 0.f, 0.f};
    #pragma unroll
    for (int kk = 0; kk < KS; ++kk) {
        const float* p = xp + kk * 32;
        short8 ahi, alo;
        #pragma unroll
        for (int j = 0; j < 8; ++j) {
            float v = p[j];
            short h = bfbits(v);
            ahi[j] = h;
            alo[j] = bfbits(v - bf2f(h));
        }
        acc = __builtin_amdgcn_mfma_f32_16x16x32_bf16(ahi, bhi[kk], acc, 0, 0, 0);
        acc = __builtin_amdgcn_mfma_f32_16x16x32_bf16(ahi, blo[kk], acc, 0, 0, 0);
        acc = __builtin_amdgcn_mfma_f32_16x16x32_bf16(alo, bhi[kk], acc, 0, 0, 0);
    }

    const int o = ntile * 16 + c;
    const float bv = bias[o];
    #pragma unroll
    for (int t = 0; t < 4; ++t) {
        int r = mt * 16 + q * 4 + t;
        if (r < NG) {
            float v = acc[t] + bv;
            if (RELU) v = v > 0.f ? v : 0.f;
            if (SPLITOUT) {
                if (o < 64) Y[(long)r * 64 + o] = v;
                else        Y[(long)NG * 64 + (long)r * 64 + (o - 64)] = v;
            } else {
                Y[(long)r * NO + o] = v;
            }
        }
    }
}

// Old shuffle-based FC (fallback path only)
__global__ void k_fc(const float* __restrict__ pooled,
                     const float* __restrict__ Wf1, const float* __restrict__ bf1,
                     const float* __restrict__ Wf2, const float* __restrict__ bf2,
                     float* __restrict__ outp) {
    const int lane = threadIdx.x & 63;
    int gw = (blockIdx.x * blockDim.x + threadIdx.x) >> 6;
    int nw = (gridDim.x * blockDim.x) >> 6;
    for (int g = gw; g < NG; g += nw) {
        float pl = pooled[(long)g * 64 + lane];
        float f1a = bf1[lane], f1b = bf1[lane + 64];
        const float* w1a = Wf1 + lane * 64;
        const float* w1b = Wf1 + (lane + 64) * 64;
        #pragma unroll 8
        for (int i = 0; i < 64; ++i) {
            float pv = __shfl(pl, i);
            f1a += pv * w1a[i];
            f1b += pv * w1b[i];
        }
        f1a = f1a > 0.f ? f1a : 0.f;
        f1b = f1b > 0.f ? f1b : 0.f;
        float oa = bf2[lane], ob = bf2[lane + 64];
        const float* w2a = Wf2 + lane * 128;
        const float* w2b = Wf2 + (lane + 64) * 128;
        #pragma unroll 8
        for (int i = 0; i < 64; ++i) {
            float va = __shfl(f1a, i);
            float vb = __shfl(f1b, i);
            oa += va * w2a[i] + vb * w2a[64 + i];
            ob += va * w2b[i] + vb * w2b[64 + i];
        }
        outp[(long)g * 64 + lane] = oa;
        outp[(long)NG * 64 + (long)g * 64 + lane] = ob;
    }
}

// ===================== fast-path kernels =====================

__global__ void k_degcnt(const int* __restrict__ ei, float* __restrict__ deg,
                         int* __restrict__ dcnt) {
    int e = blockIdx.x * blockDim.x + threadIdx.x;
    if (e < NE) {
        atomicAdd(&deg[ei[e]], 1.0f);
        atomicAdd(&dcnt[ei[NE + e]], 1);
    }
}

// scanA + fused norm (deg -> 1/deg)
__global__ void k_scanA(const int* __restrict__ dcnt, int* __restrict__ offs,
                        int* __restrict__ bsum, float* __restrict__ deg) {
    int tid = threadIdx.x, b = blockIdx.x;
    int base = b * 1024 + tid * 4;
    int v[4]; int t = 0;
    #pragma unroll
    for (int k = 0; k < 4; ++k) { v[k] = (base + k < NN) ? dcnt[base + k] : 0; t += v[k]; }
    #pragma unroll
    for (int k = 0; k < 4; ++k) {
        int i = base + k;
        if (i < NN) { float d = deg[i]; deg[i] = d > 0.f ? 1.f / d : 0.f; }
    }
    __shared__ int s[256];
    s[tid] = t;
    __syncthreads();
    for (int d = 1; d < 256; d <<= 1) {
        int x = (tid >= d) ? s[tid - d] : 0;
        __syncthreads();
        s[tid] += x;
        __syncthreads();
    }
    int excl = s[tid] - t;
    int o = excl;
    #pragma unroll
    for (int k = 0; k < 4; ++k) {
        if (base + k < NN) offs[base + k] = o;
        o += v[k];
    }
    if (tid == 255) bsum[b] = s[255];
}

__global__ void k_scanB(int* __restrict__ bsum) {
    int tid = threadIdx.x;
    __shared__ int s[128];
    int val = (tid < NBLK) ? bsum[tid] : 0;
    s[tid] = val;
    __syncthreads();
    for (int d = 1; d < 128; d <<= 1) {
        int x = (tid >= d) ? s[tid - d] : 0;
        __syncthreads();
        s[tid] += x;
        __syncthreads();
    }
    bsum[tid] = s[tid] - val;
}

__global__ void k_scanC(int* __restrict__ offs, int* __restrict__ curs,
                        const int* __restrict__ bsum) {
    int tid = threadIdx.x, b = blockIdx.x;
    int base = b * 1024 + tid * 4;
    int add = bsum[b];
    #pragma unroll
    for (int k = 0; k < 4; ++k) {
        int i = base + k;
        if (i < NN) { int o = offs[i] + add; offs[i] = o; curs[i] = o; }
    }
}

// perm[pos] = edge id (dst-sorted); fused glo binary search
__global__ void k_scatter(const int* __restrict__ ei, int* __restrict__ curs,
                          int* __restrict__ perm, const int* __restrict__ batch,
                          int* __restrict__ glo) {
    int e = blockIdx.x * blockDim.x + threadIdx.x;
    if (e < NE) {
        int d = ei[NE + e];
        int pos = atomicAdd(&curs[d], 1);
        perm[pos] = e;
    }
    if (e <= NG) {
        int lo = 0, hi = NN;
        while (lo < hi) { int m = (lo + hi) >> 1; if (batch[m] < e) lo = m + 1; else hi = m; }
        glo[e] = lo;
    }
}

__global__ void k_poolg(const float* __restrict__ out2, const int* __restrict__ glo,
                        const float* __restrict__ scale, const float* __restrict__ shift,
                        float* __restrict__ pooled) {
    const int lane = threadIdx.x & 63;
    int g = (blockIdx.x * blockDim.x + threadIdx.x) >> 6;
    if (g >= NG) return;
    int lo = glo[g], hi = glo[g + 1];
    float sc = scale[lane], sh = shift[lane];
    float acc = 0.f;
    for (int n = lo; n < hi; ++n) {
        float v = out2[(long)n * 64 + lane] * sc + sh;
        acc += v > 0.f ? v : 0.f;
    }
    float m = (float)(hi - lo);
    pooled[(long)g * 64 + lane] = acc / (m > 1.f ? m : 1.f);
}

// ===================== fallback-only kernels =====================

__global__ void k_deg(const int* __restrict__ ei, float* __restrict__ deg) {
    int e = blockIdx.x * blockDim.x + threadIdx.x;
    if (e < NE) atomicAdd(&deg[ei[e]], 1.0f);
}

template <int CI, int CO>
__global__ void k_nodeadd(const float* __restrict__ xin, const float* __restrict__ Wr,
                          const float* __restrict__ b, float* __restrict__ outp) {
    constexpr int NPW = 64 / CO;
    const int lane = threadIdx.x & 63;
    const int c = lane % CO;
    const int sub = lane / CO;
    float w[CI];
    #pragma unroll
    for (int i = 0; i < CI; ++i) w[i] = Wr[c * CI + i];
    float bias = b[c];
    int gw = (blockIdx.x * blockDim.x + threadIdx.x) >> 6;
    int nw = (gridDim.x * blockDim.x) >> 6;
    for (int n0 = gw * NPW; n0 < NN; n0 += nw * NPW) {
        int n = n0 + sub;
        if (n < NN) {
            const float* xp = xin + (long)n * CI;
            float acc = outp[(long)n * CO + c] + bias;
            #pragma unroll
            for (int i = 0; i < CI; ++i) acc += xp[i] * w[i];
            outp[(long)n * CO + c] = acc;
        }
    }
}

__global__ void k_pool_at(const float* __restrict__ out2, const int* __restrict__ batch,
                          const float* __restrict__ scale, const float* __restrict__ shift,
                          float* __restrict__ gsum) {
    long t = (long)blockIdx.x * blockDim.x + threadIdx.x;
    int c = (int)(t & 63);
    long n0 = (t >> 6) * 4;
    if (n0 >= NN) return;
    float sc = scale[c], sh = shift[c];
    float acc = 0.f;
    int gprev = batch[n0];
    #pragma unroll
    for (int k = 0; k < 4; ++k) {
        long n = n0 + k;
        if (n >= NN) break;
        int g = batch[n];
        float v = out2[n * 64 + c] * sc + sh;
        v = v > 0.f ? v : 0.f;
        if (g != gprev) {
            atomicAdd(&gsum[(long)gprev * 64 + c], acc);
            acc = 0.f; gprev = g;
        }
        acc += v;
    }
    atomicAdd(&gsum[(long)gprev * 64 + c], acc);
}

__global__ void k_cnt(const int* __restrict__ batch, float* __restrict__ gcnt) {
    int n = blockIdx.x * blockDim.x + threadIdx.x;
    if (n < NN) atomicAdd(&gcnt[batch[n]], 1.0f);
}

__global__ void k_div(float* __restrict__ gsum, const float* __restrict__ gcnt) {
    long t = (long)blockIdx.x * blockDim.x + threadIdx.x;
    if (t < 64L * NG) {
        float cnt = gcnt[t >> 6];
        gsum[t] = gsum[t] / (cnt > 1.f ? cnt : 1.f);
    }
}

// ===================== host =====================

extern "C" void kernel_launch(void* const* d_in, const int* in_sizes, int n_in,
                              void* d_out, int out_size, void* d_ws, size_t ws_size,
                              hipStream_t stream) {
    const float* x   = (const float*)d_in[0];
    const int*   ei  = (const int*)d_in[1];
    const float* ea  = (const float*)d_in[2];
    const int*   bat = (const int*)d_in[3];
    const float* We1 = (const float*)d_in[4];
    const float* b1  = (const float*)d_in[5];
    const float* Wr1 = (const float*)d_in[6];
    const float* g1  = (const float*)d_in[7];
    const float* be1 = (const float*)d_in[8];
    const float* We2 = (const float*)d_in[9];
    const float* b2  = (const float*)d_in[10];
    const float* Wr2 = (const float*)d_in[11];
    const float* g2  = (const float*)d_in[12];
    const float* be2 = (const float*)d_in[13];
    const float* Wf1 = (const float*)d_in[14];
    const float* bf1 = (const float*)d_in[15];
    const float* Wf2 = (const float*)d_in[16];
    const float* bf2 = (const float*)d_in[17];
    float* out = (float*)d_out;
    float* ws  = (float*)d_ws;
    int*   wsi = (int*)d_ws;

    if (ws_size >= (size_t)TOTAL_FAST * sizeof(float)) {
        float* nrm    = ws + FZ_NRM;
        float* st     = ws + FZ_STAT;
        int*   dcnt   = wsi + FZ_DCNT;
        int*   offs   = wsi + O_OFFS;
        int*   curs   = wsi + O_CURS;
        int*   perm   = wsi + O_PERM;
        int*   glo    = wsi + O_GLO;
        int*   bsum   = wsi + O_BSUM;
        float* pooled = ws + O_POOL;
        float* h1     = ws + O_H1;
        float* out2   = ws + O_OUT2;
        unsigned short* msg1 = (unsigned short*)(ws + O_OUT2);  // disjoint lifetime
        unsigned short* msg2 = (unsigned short*)(ws + O_MSG2);
        unsigned short* h1b  = (unsigned short*)(ws + O_H1B);
        float* fc1out = ws + O_MSG2;   // reuses msg2 region (dead after k_msum<64>)
        float* sums1 = st;        float* ssq1 = st + 32;
        float* sums2 = st + 64;   float* ssq2 = st + 128;
        float* sc1   = st + 192;  float* sh1  = st + 224;
        float* sc2   = st + 256;  float* sh2  = st + 320;

        hipMemsetAsync(d_ws, 0, (size_t)ZN_FAST * sizeof(float), stream);

        k_degcnt<<<(NE + 255) / 256, 256, 0, stream>>>(ei, nrm, dcnt);
        k_scanA<<<NBLK, 256, 0, stream>>>(dcnt, offs, bsum, nrm);
        k_scanB<<<1, 128, 0, stream>>>(bsum);
        k_scanC<<<NBLK, 256, 0, stream>>>(offs, curs, bsum);
        k_scatter<<<(NE + 255) / 256, 256, 0, stream>>>(ei, curs, perm, bat, glo);

        // ---- layer 1 ----
        k_edge_lds<16, 32, false><<<2048, 128, 0, stream>>>(
            ei, ea, x, We1, nrm, msg1);
        k_msum<32><<<3125, 256, 0, stream>>>(msg1, offs, dcnt, perm, h1);
        k_root<16, 32, false><<<512, 256, 0, stream>>>(
            x, Wr1, b1, h1, sums1, ssq1);
        k_fin<<<1, 64, 0, stream>>>(32, sums1, ssq1, g1, be1, sc1, sh1);
        // h1 -> h1b (bf16, BN+relu folded)
        k_h1b<<<(int)((32L * NN / 8 + 255) / 256), 256, 0, stream>>>(h1, sc1, sh1, h1b);

        // ---- layer 2 (inputs pre-normalized bf16) ----
        k_edge_lds<32, 64, true><<<2048, 256, 0, stream>>>(
            ei, ea, h1b, We2, nrm, msg2);
        k_msum<64><<<6250, 256, 0, stream>>>(msg2, offs, dcnt, perm, out2);
        k_root<32, 64, true><<<512, 256, 0, stream>>>(
            h1b, Wr2, b2, out2, sums2, ssq2);
        k_fin<<<1, 64, 0, stream>>>(64, sums2, ssq2, g2, be2, sc2, sh2);

        k_poolg<<<1250, 256, 0, stream>>>(out2, glo, sc2, sh2, pooled);

        {
            constexpr int MT = (NG + 15) / 16;      // 313
            k_fcmm<64, 128, true,  false><<<(MT * 8 + 3) / 4, 256, 0, stream>>>(pooled, Wf1, bf1, fc1out);
            k_fcmm<128, 128, false, true><<<(MT * 8 + 3) / 4, 256, 0, stream>>>(fc1out, Wf2, bf2, out);
        }
    } else {
        float* nrm   = ws + B_NORM;
        float* agg1  = ws + B_AGG1;
        float* agg2  = ws + B_AGG2;
        float* gsum  = ws + B_GSUM;
        float* gcnt  = ws + B_GCNT;
        float* st    = ws + B_STAT;
        float* sums1 = st;        float* ssq1 = st + 32;
        float* sums2 = st + 64;   float* ssq2 = st + 128;
        float* sc1   = st + 192;  float* sh1  = st + 224;
        float* sc2   = st + 256;  float* sh2  = st + 320;

        hipMemsetAsync(d_ws, 0, (size_t)ZERO_FB * sizeof(float), stream);

        k_deg<<<(NE + 255) / 256, 256, 0, stream>>>(ei, nrm);
        k_norm<<<(NN + 255) / 256, 256, 0, stream>>>(nrm);

        k_edge_mfma_at<4, 32><<<6250, 256, 0, stream>>>(ei, ea, x, We1, nrm, agg1);
        k_nodeadd<16, 32><<<1024, 256, 0, stream>>>(x, Wr1, b1, agg1);
        k_colstats<32><<<1024, 256, 0, stream>>>(agg1, sums1, ssq1);
        k_fin<<<1, 64, 0, stream>>>(32, sums1, ssq1, g1, be1, sc1, sh1);
        k_bnrelu32<<<(int)((32L * NN + 255) / 256), 256, 0, stream>>>(agg1, sc1, sh1, agg1);

        k_edge_mfma_at<8, 64><<<12500, 256, 0, stream>>>(ei, ea, agg1, We2, nrm, agg2);
        k_nodeadd<32, 64><<<1024, 256, 0, stream>>>(agg1, Wr2, b2, agg2);
        k_colstats<64><<<1024, 256, 0, stream>>>(agg2, sums2, ssq2);
        k_fin<<<1, 64, 0, stream>>>(64, sums2, ssq2, g2, be2, sc2, sh2);

        k_pool_at<<<6250, 256, 0, stream>>>(agg2, bat, sc2, sh2, gsum);
        k_cnt<<<(NN + 255) / 256, 256, 0, stream>>>(bat, gcnt);
        k_div<<<(int)((64L * NG + 255) / 256), 256, 0, stream>>>(gsum, gcnt);
        k_fc<<<1250, 256, 0, stream>>>(gsum, Wf1, bf1, Wf2, bf2, out);
    }
}

// Round 16
// 184.393 us; speedup vs baseline: 1.2427x; 1.0340x over previous
//
#include <hip/hip_runtime.h>

#define NN 100000
#define NE 200000
#define NG 5000
#define EPSI 1e-5f
#define NBLK 98   // ceil(NN/1024)

using short8 = __attribute__((ext_vector_type(8))) short;
using f32x4  = __attribute__((ext_vector_type(4))) float;

static __device__ inline short bfbits(float f) {
    __bf16 b = (__bf16)f;
    return __builtin_bit_cast(short, b);
}
static __device__ inline float bf2f(short s) {
    unsigned u = ((unsigned)(unsigned short)s) << 16;
    return __builtin_bit_cast(float, u);
}

// ===================== FAST-PATH workspace layout (floats) =====================
constexpr long FZ_NRM  = 0;                         // NN floats (src deg -> norm)
constexpr long FZ_STAT = NN;                        // 512 floats
constexpr long FZ_DCNT = NN + 512;                  // NN ints (dst count)
constexpr long ZN_FAST = 2L * NN + 512;             // zeroed region (~0.8 MB)
constexpr long O_OFFS  = ZN_FAST;                   // NN int
constexpr long O_CURS  = O_OFFS + NN;               // NN int
constexpr long O_PERM  = O_CURS + NN;               // NE int (dst-sorted edge ids)
constexpr long O_GLO   = O_PERM + NE;               // NG+1 int
constexpr long O_BSUM  = O_GLO + NG + 1;            // 256 int
constexpr long O_POOL  = ((O_BSUM + 256 + 3) & ~3L);// 64*NG float (16B-aligned)
constexpr long O_H1    = O_POOL + 64L * NG;         // 32*NN float
constexpr long O_OUT2  = O_H1 + 32L * NN;           // 64*NN float (also msg1 bf16, disjoint)
constexpr long O_MSG2  = O_OUT2 + 64L * NN;         // msg2 bf16 (32*NE floats worth)
constexpr long O_H1B   = O_MSG2 + 32L * NE;         // h1b bf16 (16*NN floats worth)
constexpr long TOTAL_FAST = O_MSG2 + 64L * NE;      // ~23.33M floats = 93.3 MB

// ===================== FALLBACK workspace layout (floats) ======================
constexpr long B_NORM = 0;
constexpr long B_AGG1 = NN;
constexpr long B_AGG2 = B_AGG1 + 32L * NN;
constexpr long B_GSUM = B_AGG2 + 64L * NN;
constexpr long B_GCNT = B_GSUM + 64L * NG;
constexpr long B_STAT = B_GCNT + NG;
constexpr long ZERO_FB = B_STAT + 512;

// ===================== shared kernels =====================

__global__ void k_norm(float* __restrict__ deg) {
    int n = blockIdx.x * blockDim.x + threadIdx.x;
    if (n < NN) { float d = deg[n]; deg[n] = d > 0.f ? 1.f / d : 0.f; }
}

// ---------------------------------------------------------------------------
// Edge messages via MFMA. Groups of 32 edges; T14 async-STAGE split (ei 2
// groups ahead, data 1 group ahead; vmcnt wait after compute). HB: h input
// is BF16 (BN pre-applied). msg stored BF16 in edge order (coalesced).
// ---------------------------------------------------------------------------
template <int CI, int COLS, bool HB>
__global__ void __launch_bounds__(64 * (COLS / 16))
k_edge_lds(const int* __restrict__ ei, const float* __restrict__ ea,
           const void* __restrict__ hraw, const float* __restrict__ W,
           const float* __restrict__ nrm, unsigned short* __restrict__ msg)
{
    constexpr int KS = CI / 4;
    constexpr int TILES = COLS / 16;
    constexpr int BT = 64 * TILES;
    constexpr int HP  = 20;               // f32 pitch (CI=16 path)
    constexpr int HPB = 36;               // bf16 pitch (CI=32 path)
    constexpr int NGRP = NE / 32;         // 6250
    constexpr int TPR = BT / 32;
    constexpr int EPT = 256 / BT;
    constexpr int HBYTES = HB ? (32 * HPB * 2) : (32 * HP * 4);

    const int tid  = threadIdx.x;
    const int lane = tid & 63;
    const int wid  = tid >> 6;
    const int c = lane & 15;
    const int q = lane >> 4;

    short8 bfr[KS];
    {
        const float* wrow = W + (wid * 16 + c) * (CI * 8) + q * 8;
        #pragma unroll
        for (int kk = 0; kk < KS; ++kk) {
            const float* p = wrow + kk * 32;
            #pragma unroll
            for (int j = 0; j < 8; ++j) bfr[kk][j] = bfbits(p[j]);
        }
    }

    __shared__ __align__(16) unsigned char h_raw[2][HBYTES];
    __shared__ float ea_lds[2][32 * 9];

    const int hrow = tid / TPR;           // 0..31
    const int hj0  = (tid % TPR) * 4;     // 4-elem chunk
    const int erow = tid >> 3;
    const int ef   = tid & 7;

    auto writebuf = [&](int buf, float4 hv, ushort4 hu, float ev0, float ev1) {
        if constexpr (HB) {
            *reinterpret_cast<ushort4*>(
                (unsigned short*)h_raw[buf] + hrow * HPB + hj0) = hu;
        } else {
            *reinterpret_cast<float4*>(
                (float*)h_raw[buf] + hrow * HP + hj0) = hv;
        }
        ea_lds[buf][erow * 9 + ef] = ev0;
        if constexpr (EPT == 2) ea_lds[buf][(erow + 16) * 9 + ef] = ev1;
    };

    auto compute = [&](int buf, long e0) {
        #pragma unroll
        for (int et = 0; et < 2; ++et) {
            const int r = et * 16 + c;
            float ev[8];
            #pragma unroll
            for (int j = 0; j < 8; ++j) ev[j] = ea_lds[buf][r * 9 + j];
            f32x4 acc = {0.f, 0.f, 0.f, 0.f};
            #pragma unroll
            for (int kk = 0; kk < KS; ++kk) {
                float hv;
                if constexpr (HB)
                    hv = bf2f((short)((const unsigned short*)h_raw[buf])[r * HPB + kk * 4 + q]);
                else
                    hv = ((const float*)h_raw[buf])[r * HP + kk * 4 + q];
                short8 afr;
                #pragma unroll
                for (int j = 0; j < 8; ++j) afr[j] = bfbits(hv * ev[j]);
                acc = __builtin_amdgcn_mfma_f32_16x16x32_bf16(afr, bfr[kk], acc, 0, 0, 0);
            }
            #pragma unroll
            for (int t = 0; t < 4; ++t) {
                msg[(e0 + et * 16 + q * 4 + t) * COLS + wid * 16 + c] =
                    (unsigned short)bfbits(acc[t]);
            }
        }
    };

    const int GD = gridDim.x;
    int g = blockIdx.x;
    if (g >= NGRP) return;

    // ---- prologue ----
    int sh_c = ei[(long)g * 32 + hrow];
    int se0_c = ei[(long)g * 32 + erow];
    int se1_c = 0;
    if constexpr (EPT == 2) se1_c = ei[(long)g * 32 + erow + 16];
    int sh_n = 0, se0_n = 0, se1_n = 0;
    {
        int gn0 = g + GD;
        if (gn0 < NGRP) {
            sh_n = ei[(long)gn0 * 32 + hrow];
            se0_n = ei[(long)gn0 * 32 + erow];
            if constexpr (EPT == 2) se1_n = ei[(long)gn0 * 32 + erow + 16];
        }
    }
    float4 hv4 = {0.f, 0.f, 0.f, 0.f};
    ushort4 hu4 = {0, 0, 0, 0};
    float ev0 = 0.f, ev1 = 0.f;
    {
        if constexpr (HB)
            hu4 = *reinterpret_cast<const ushort4*>(
                (const unsigned short*)hraw + (long)sh_c * CI + hj0);
        else
            hv4 = *reinterpret_cast<const float4*>(
                (const float*)hraw + (long)sh_c * CI + hj0);
        ev0 = ea[((long)g * 32 + erow) * 8 + ef] * nrm[se0_c];
        if constexpr (EPT == 2)
            ev1 = ea[((long)g * 32 + erow + 16) * 8 + ef] * nrm[se1_c];
    }
    writebuf(0, hv4, hu4, ev0, ev1);
    __syncthreads();

    int p = 0;
    for (;;) {
        int gn = g + GD;
        bool more = (gn < NGRP);
        int gnn = gn + GD;
        int sh_f = 0, se0_f = 0, se1_f = 0;
        if (gnn < NGRP) {
            sh_f = ei[(long)gnn * 32 + hrow];
            se0_f = ei[(long)gnn * 32 + erow];
            if constexpr (EPT == 2) se1_f = ei[(long)gnn * 32 + erow + 16];
        }
        if (more) {
            if constexpr (HB)
                hu4 = *reinterpret_cast<const ushort4*>(
                    (const unsigned short*)hraw + (long)sh_n * CI + hj0);
            else
                hv4 = *reinterpret_cast<const float4*>(
                    (const float*)hraw + (long)sh_n * CI + hj0);
            ev0 = ea[((long)gn * 32 + erow) * 8 + ef] * nrm[se0_n];
            if constexpr (EPT == 2)
                ev1 = ea[((long)gn * 32 + erow + 16) * 8 + ef] * nrm[se1_n];
        }
        compute(p, (long)g * 32);
        if (!more) break;
        writebuf(p ^ 1, hv4, hu4, ev0, ev1);
        __syncthreads();
        sh_n = sh_f; se0_n = se0_f; se1_n = se1_f;
        g = gn; p ^= 1;
    }
}

// Fallback atomic-scatter MFMA edge kernel
template <int KS, int COLS>
__global__ void __launch_bounds__(256) k_edge_mfma_at(
    const int* __restrict__ ei, const float* __restrict__ ea,
    const float* __restrict__ h, const float* __restrict__ W,
    const float* __restrict__ nrm, float* __restrict__ outp)
{
    constexpr int TILES = COLS / 16;
    constexpr int CI = KS * 4;
    const int lane = threadIdx.x & 63;
    const int wid  = threadIdx.x >> 6;
    const int c = lane & 15;
    const int q = lane >> 4;
    const int gw = blockIdx.x * 4 + wid;
    const int ntile = gw % TILES;
    const int grp   = gw / TILES;
    if (grp >= NE / 16) return;
    short8 bfr[KS];
    {
        const float* wrow = W + (ntile * 16 + c) * (KS * 32) + q * 8;
        #pragma unroll
        for (int kk = 0; kk < KS; ++kk) {
            const float* p = wrow + kk * 32;
            #pragma unroll
            for (int j = 0; j < 8; ++j) bfr[kk][j] = bfbits(p[j]);
        }
    }
    const long e0 = (long)grp * 16;
    const long e  = e0 + c;
    const int  s  = ei[e];
    const float nv = nrm[s];
    float ev[8];
    {
        const float* p = ea + e * 8;
        #pragma unroll
        for (int j = 0; j < 8; ++j) ev[j] = p[j];
    }
    float hv[KS];
    {
        const float* hp = h + (long)s * CI + q;
        #pragma unroll
        for (int kk = 0; kk < KS; ++kk) hv[kk] = hp[kk * 4] * nv;
    }
    f32x4 acc = {0.f, 0.f, 0.f, 0.f};
    #pragma unroll
    for (int kk = 0; kk < KS; ++kk) {
        short8 afr;
        #pragma unroll
        for (int j = 0; j < 8; ++j) afr[j] = bfbits(hv[kk] * ev[j]);
        acc = __builtin_amdgcn_mfma_f32_16x16x32_bf16(afr, bfr[kk], acc, 0, 0, 0);
    }
    #pragma unroll
    for (int t = 0; t < 4; ++t) {
        int m = q * 4 + t;
        int d = ei[NE + e0 + m];
        atomicAdd(&outp[(long)d * COLS + ntile * 16 + c], acc[t]);
    }
}

template <int C>
__global__ void k_colstats(const float* __restrict__ v, float* __restrict__ sum,
                           float* __restrict__ ssq) {
    constexpr int RPB = 256 / C;
    const int c = threadIdx.x % C;
    const int r = threadIdx.x / C;
    float s = 0.f, q = 0.f;
    for (int n = blockIdx.x * RPB + r; n < NN; n += gridDim.x * RPB) {
        float val = v[(long)n * C + c];
        s += val; q += val * val;
    }
    __shared__ float ls[256], lq[256];
    ls[threadIdx.x] = s; lq[threadIdx.x] = q;
    __syncthreads();
    if (threadIdx.x < C) {
        float ts = 0.f, tq = 0.f;
        #pragma unroll
        for (int k = 0; k < RPB; ++k) { ts += ls[c + k * C]; tq += lq[c + k * C]; }
        atomicAdd(&sum[c], ts);
        atomicAdd(&ssq[c], tq);
    }
}

__global__ void k_fin(int C, const float* __restrict__ sum, const float* __restrict__ ssq,
                      const float* __restrict__ g, const float* __restrict__ be,
                      float* __restrict__ scale, float* __restrict__ shift) {
    int c = threadIdx.x;
    if (c < C) {
        float mu  = sum[c] / (float)NN;
        float var = ssq[c] / (float)NN - mu * mu;
        float rs  = rsqrtf(var + EPSI);
        float sc  = rs * g[c];
        scale[c] = sc;
        shift[c] = be[c] - mu * sc;
    }
}

__global__ void k_bnrelu32(const float* __restrict__ in, const float* __restrict__ scale,
                           const float* __restrict__ shift, float* __restrict__ outp) {
    long t = (long)blockIdx.x * blockDim.x + threadIdx.x;
    if (t < 32L * NN) {
        int c = (int)(t & 31);
        float v = in[t] * scale[c] + shift[c];
        outp[t] = v > 0.f ? v : 0.f;
    }
}

// h1 (f32) -> h1b (bf16) with BN+relu; BN coefficients computed in-block
// from raw sums/ssq (fin fused).
__global__ void __launch_bounds__(256) k_h1b(
    const float* __restrict__ h1, const float* __restrict__ sums,
    const float* __restrict__ ssq, const float* __restrict__ g,
    const float* __restrict__ be, unsigned short* __restrict__ h1b)
{
    __shared__ float sc[32], sh[32];
    if (threadIdx.x < 32) {
        int c = threadIdx.x;
        float mu  = sums[c] / (float)NN;
        float var = ssq[c] / (float)NN - mu * mu;
        float rs  = rsqrtf(var + EPSI);
        float s   = rs * g[c];
        sc[c] = s;
        sh[c] = be[c] - mu * s;
    }
    __syncthreads();
    long t = (long)blockIdx.x * 256 + threadIdx.x;
    long base = t * 8;
    if (base >= 32L * NN) return;
    int c0 = (int)(base & 31);
    short8 outv;
    const float* p = h1 + base;
    #pragma unroll
    for (int j = 0; j < 8; ++j) {
        float v = fmaxf(fmaf(p[j], sc[c0 + j], sh[c0 + j]), 0.f);
        outv[j] = bfbits(v);
    }
    *reinterpret_cast<short8*>(h1b + base) = outv;
}

// ---------------------------------------------------------------------------
// Segment-sum with perm gather over BF16 messages: thread = (node, 4-ch chunk).
// ---------------------------------------------------------------------------
template <int CO>
__global__ void __launch_bounds__(256) k_msum(
    const unsigned short* __restrict__ msg, const int* __restrict__ offs,
    const int* __restrict__ dcnt, const int* __restrict__ perm,
    float* __restrict__ aggout)
{
    constexpr int CPN = CO / 4;
    long t = (long)blockIdx.x * 256 + threadIdx.x;
    long n = t / CPN;
    int chunk = (int)(t % CPN);
    if (n >= NN) return;
    int lo = offs[n], ct = dcnt[n];
    f32x4 a = {0.f, 0.f, 0.f, 0.f}, b = {0.f, 0.f, 0.f, 0.f};
    int j = 0;
    for (; j + 1 < ct; j += 2) {
        int e0p = perm[lo + j];
        int e1p = perm[lo + j + 1];
        ushort4 u0 = *reinterpret_cast<const ushort4*>(msg + (long)e0p * CO + chunk * 4);
        ushort4 u1 = *reinterpret_cast<const ushort4*>(msg + (long)e1p * CO + chunk * 4);
        a.x += bf2f((short)u0.x); a.y += bf2f((short)u0.y);
        a.z += bf2f((short)u0.z); a.w += bf2f((short)u0.w);
        b.x += bf2f((short)u1.x); b.y += bf2f((short)u1.y);
        b.z += bf2f((short)u1.z); b.w += bf2f((short)u1.w);
    }
    if (j < ct) {
        int e0p = perm[lo + j];
        ushort4 u0 = *reinterpret_cast<const ushort4*>(msg + (long)e0p * CO + chunk * 4);
        a.x += bf2f((short)u0.x); a.y += bf2f((short)u0.y);
        a.z += bf2f((short)u0.z); a.w += bf2f((short)u0.w);
    }
    a += b;
    *reinterpret_cast<f32x4*>(aggout + n * CO + chunk * 4) = a;
}

// ---------------------------------------------------------------------------
// Root transform as streaming MFMA GEMM, fused: in-place add onto msum
// output + bias + column stats (raw sums/ssq). XB: X is BF16 -> 1 MFMA.
// ---------------------------------------------------------------------------
template <int CI, int CO, bool XB>
__global__ void __launch_bounds__(256) k_root(
    const void* __restrict__ Xraw, const float* __restrict__ W,
    const float* __restrict__ bias, float* __restrict__ Y,
    float* __restrict__ sum, float* __restrict__ ssq)
{
    constexpr int TILES = CO / 16;        // 4 (CO=64) or 2 (CO=32)
    constexpr int MT = NN / 16;           // 6250
    constexpr int MTPB = 4 / TILES;
    const int lane = threadIdx.x & 63;
    const int wid  = threadIdx.x >> 6;
    const int c = lane & 15;
    const int q = lane >> 4;
    const int ntile = (TILES == 4) ? wid : (wid & (TILES - 1));
    const int mtoff = (TILES == 4) ? 0 : (wid >> 1);
    const int o = ntile * 16 + c;
    const bool kvalid = (q * 8) < CI;

    short8 bhi = {0,0,0,0,0,0,0,0}, blo = {0,0,0,0,0,0,0,0};
    if (kvalid) {
        const float* wrow = W + (long)o * CI + q * 8;
        #pragma unroll
        for (int j = 0; j < 8; ++j) {
            float v = wrow[j];
            short h = bfbits(v);
            bhi[j] = h;
            blo[j] = bfbits(v - bf2f(h));
        }
    }
    const float bv = bias[o];
    float s_acc = 0.f, q_acc = 0.f;

    for (int mt = blockIdx.x * MTPB + mtoff; mt < MT; mt += gridDim.x * MTPB) {
        f32x4 acc = {0.f, 0.f, 0.f, 0.f};
        if constexpr (XB) {
            short8 ahi = {0,0,0,0,0,0,0,0};
            if (kvalid)
                ahi = *reinterpret_cast<const short8*>(
                    (const unsigned short*)Xraw + (long)(mt * 16 + c) * CI + q * 8);
            acc = __builtin_amdgcn_mfma_f32_16x16x32_bf16(ahi, bhi, acc, 0, 0, 0);
        } else {
            short8 ahi = {0,0,0,0,0,0,0,0}, alo = {0,0,0,0,0,0,0,0};
            if (kvalid) {
                const float* xp = (const float*)Xraw + (long)(mt * 16 + c) * CI + q * 8;
                #pragma unroll
                for (int j = 0; j < 8; ++j) {
                    float v = xp[j];
                    short h = bfbits(v);
                    ahi[j] = h;
                    alo[j] = bfbits(v - bf2f(h));
                }
            }
            acc = __builtin_amdgcn_mfma_f32_16x16x32_bf16(ahi, bhi, acc, 0, 0, 0);
            acc = __builtin_amdgcn_mfma_f32_16x16x32_bf16(ahi, blo, acc, 0, 0, 0);
            acc = __builtin_amdgcn_mfma_f32_16x16x32_bf16(alo, bhi, acc, 0, 0, 0);
        }
        #pragma unroll
        for (int t4 = 0; t4 < 4; ++t4) {
            long r = (long)mt * 16 + q * 4 + t4;
            long idx = r * CO + o;
            float v = Y[idx] + acc[t4] + bv;
            Y[idx] = v;
            s_acc += v;
            q_acc = fmaf(v, v, q_acc);
        }
    }

    __shared__ float ls[256], lq[256];
    ls[threadIdx.x] = s_acc; lq[threadIdx.x] = q_acc;
    __syncthreads();
    if (threadIdx.x < CO) {
        int ch = threadIdx.x;
        int bw = ch >> 4;
        int cc = ch & 15;
        float ts = 0.f, tq = 0.f;
        if (TILES == 4) {
            #pragma unroll
            for (int q2 = 0; q2 < 4; ++q2) {
                ts += ls[bw * 64 + q2 * 16 + cc];
                tq += lq[bw * 64 + q2 * 16 + cc];
            }
        } else {
            #pragma unroll
            for (int w2 = 0; w2 < 2; ++w2) {
                int w = bw + w2 * 2;
                #pragma unroll
                for (int q2 = 0; q2 < 4; ++q2) {
                    ts += ls[w * 64 + q2 * 16 + cc];
                    tq += lq[w * 64 + q2 * 16 + cc];
                }
            }
        }
        atomicAdd(&sum[ch], ts);
        atomicAdd(&ssq[ch], tq);
    }
}

// ---------------------------------------------------------------------------
// bn2+relu+mean-pool with fin fused (per-lane coefficient computation).
// ---------------------------------------------------------------------------
__global__ void k_poolg(const float* __restrict__ out2, const int* __restrict__ glo,
                        const float* __restrict__ sums, const float* __restrict__ ssq,
                        const float* __restrict__ g2, const float* __restrict__ be2,
                        float* __restrict__ pooled) {
    const int lane = threadIdx.x & 63;
    int g = (blockIdx.x * blockDim.x + threadIdx.x) >> 6;
    if (g >= NG) return;
    float mu  = sums[lane] / (float)NN;
    float var = ssq[lane] / (float)NN - mu * mu;
    float rs  = rsqrtf(var + EPSI);
    float sc  = rs * g2[lane];
    float sh  = be2[lane] - mu * sc;
    int lo = glo[g], hi = glo[g + 1];
    float acc = 0.f;
    for (int n = lo; n < hi; ++n) {
        float v = out2[(long)n * 64 + lane] * sc + sh;
        acc += v > 0.f ? v : 0.f;
    }
    float m = (float)(hi - lo);
    pooled[(long)g * 64 + lane] = acc / (m > 1.f ? m : 1.f);
}

// ---------------------------------------------------------------------------
// FUSED FC: block = one 16-row tile. 4 waves compute fc1 (8 ntiles, K=64)
// into LDS, sync, then fc2 (8 ntiles, K=128) from LDS. Split-bf16 accuracy.
// ---------------------------------------------------------------------------
__global__ void __launch_bounds__(256) k_fcfused(
    const float* __restrict__ pooled,
    const float* __restrict__ Wf1, const float* __restrict__ bf1,
    const float* __restrict__ Wf2, const float* __restrict__ bf2,
    float* __restrict__ outp)
{
    constexpr int MT = (NG + 15) / 16;   // 313
    const int lane = threadIdx.x & 63;
    const int wid  = threadIdx.x >> 6;
    const int c = lane & 15;
    const int q = lane >> 4;
    const int mt = blockIdx.x;
    if (mt >= MT) return;

    __shared__ float f1[16][132];   // fc1 output tile, padded

    int arow = mt * 16 + c;
    if (arow > NG - 1) arow = NG - 1;

    // ---- fc1: wave handles ntiles wid*2, wid*2+1 (K=64, KS=2) ----
    #pragma unroll
    for (int nt2 = 0; nt2 < 2; ++nt2) {
        const int o = (wid * 2 + nt2) * 16 + c;
        short8 bhi[2], blo[2];
        #pragma unroll
        for (int kk = 0; kk < 2; ++kk) {
            const float* p = Wf1 + (long)o * 64 + kk * 32 + q * 8;
            #pragma unroll
            for (int j = 0; j < 8; ++j) {
                float v = p[j];
                short h = bfbits(v);
                bhi[kk][j] = h;
                blo[kk][j] = bfbits(v - bf2f(h));
            }
        }
        const float* xp = pooled + (long)arow * 64 + q * 8;
        f32x4 acc = {0.f, 0.f, 0.f, 0.f};
        #pragma unroll
        for (int kk = 0; kk < 2; ++kk) {
            const float* p = xp + kk * 32;
            short8 ahi, alo;
            #pragma unroll
            for (int j = 0; j < 8; ++j) {
                float v = p[j];
                short h = bfbits(v);
                ahi[j] = h;
                alo[j] = bfbits(v - bf2f(h));
            }
            acc = __builtin_amdgcn_mfma_f32_16x16x32_bf16(ahi, bhi[kk], acc, 0, 0, 0);
            acc = __builtin_amdgcn_mfma_f32_16x16x32_bf16(ahi, blo[kk], acc, 0, 0, 0);
            acc = __builtin_amdgcn_mfma_f32_16x16x32_bf16(alo, bhi[kk], acc, 0, 0, 0);
        }
        const float bv = bf1[o];
        #pragma unroll
        for (int t = 0; t < 4; ++t) {
            float v = acc[t] + bv;
            f1[q * 4 + t][o] = v > 0.f ? v : 0.f;
        }
    }
    __syncthreads();

    // ---- fc2: wave handles ntiles wid*2, wid*2+1 (K=128, KS=4), A from LDS ----
    #pragma unroll
    for (int nt2 = 0; nt2 < 2; ++nt2) {
        const int o = (wid * 2 + nt2) * 16 + c;
        f32x4 acc = {0.f, 0.f, 0.f, 0.f};
        #pragma unroll
        for (int kk = 0; kk < 4; ++kk) {
            short8 bhi, blo;
            {
                const float* p = Wf2 + (long)o * 128 + kk * 32 + q * 8;
                #pragma unroll
                for (int j = 0; j < 8; ++j) {
                    float v = p[j];
                    short h = bfbits(v);
                    bhi[j] = h;
                    blo[j] = bfbits(v - bf2f(h));
                }
            }
            short8 ahi, alo;
            {
                const float* p = &f1[c][kk * 32 + q * 8];
                #pragma unroll
                for (int j = 0; j < 8; ++j) {
                    float v = p[j];
                    short h = bfbits(v);
                    ahi[j] = h;
                    alo[j] = bfbits(v - bf2f(h));
                }
            }
            acc = __builtin_amdgcn_mfma_f32_16x16x32_bf16(ahi, bhi, acc, 0, 0, 0);
            acc = __builtin_amdgcn_mfma_f32_16x16x32_bf16(ahi, blo, acc, 0, 0, 0);
            acc = __builtin_amdgcn_mfma_f32_16x16x32_bf16(alo, bhi, acc, 0, 0, 0);
        }
        const float bv = bf2[o];
        #pragma unroll
        for (int t = 0; t < 4; ++t) {
            int r = mt * 16 + q * 4 + t;
            if (r < NG) {
                float v = acc[t] + bv;
                if (o < 64) outp[(long)r * 64 + o] = v;
                else        outp[(long)NG * 64 + (long)r * 64 + (o - 64)] = v;
            }
        }
    }
}

// Old shuffle-based FC (fallback path only)
__global__ void k_fc(const float* __restrict__ pooled,
                     const float* __restrict__ Wf1, const float* __restrict__ bf1,
                     const float* __restrict__ Wf2, const float* __restrict__ bf2,
                     float* __restrict__ outp) {
    const int lane = threadIdx.x & 63;
    int gw = (blockIdx.x * blockDim.x + threadIdx.x) >> 6;
    int nw = (gridDim.x * blockDim.x) >> 6;
    for (int g = gw; g < NG; g += nw) {
        float pl = pooled[(long)g * 64 + lane];
        float f1a = bf1[lane], f1b = bf1[lane + 64];
        const float* w1a = Wf1 + lane * 64;
        const float* w1b = Wf1 + (lane + 64) * 64;
        #pragma unroll 8
        for (int i = 0; i < 64; ++i) {
            float pv = __shfl(pl, i);
            f1a += pv * w1a[i];
            f1b += pv * w1b[i];
        }
        f1a = f1a > 0.f ? f1a : 0.f;
        f1b = f1b > 0.f ? f1b : 0.f;
        float oa = bf2[lane], ob = bf2[lane + 64];
        const float* w2a = Wf2 + lane * 128;
        const float* w2b = Wf2 + (lane + 64) * 128;
        #pragma unroll 8
        for (int i = 0; i < 64; ++i) {
            float va = __shfl(f1a, i);
            float vb = __shfl(f1b, i);
            oa += va * w2a[i] + vb * w2a[64 + i];
            ob += va * w2b[i] + vb * w2b[64 + i];
        }
        outp[(long)g * 64 + lane] = oa;
        outp[(long)NG * 64 + (long)g * 64 + lane] = ob;
    }
}

// ===================== fast-path kernels =====================

__global__ void k_degcnt(const int* __restrict__ ei, float* __restrict__ deg,
                         int* __restrict__ dcnt) {
    int e = blockIdx.x * blockDim.x + threadIdx.x;
    if (e < NE) {
        atomicAdd(&deg[ei[e]], 1.0f);
        atomicAdd(&dcnt[ei[NE + e]], 1);
    }
}

// scanA + fused norm (deg -> 1/deg); bsum holds RAW block sums
__global__ void k_scanA(const int* __restrict__ dcnt, int* __restrict__ offs,
                        int* __restrict__ bsum, float* __restrict__ deg) {
    int tid = threadIdx.x, b = blockIdx.x;
    int base = b * 1024 + tid * 4;
    int v[4]; int t = 0;
    #pragma unroll
    for (int k = 0; k < 4; ++k) { v[k] = (base + k < NN) ? dcnt[base + k] : 0; t += v[k]; }
    #pragma unroll
    for (int k = 0; k < 4; ++k) {
        int i = base + k;
        if (i < NN) { float d = deg[i]; deg[i] = d > 0.f ? 1.f / d : 0.f; }
    }
    __shared__ int s[256];
    s[tid] = t;
    __syncthreads();
    for (int d = 1; d < 256; d <<= 1) {
        int x = (tid >= d) ? s[tid - d] : 0;
        __syncthreads();
        s[tid] += x;
        __syncthreads();
    }
    int excl = s[tid] - t;
    int o = excl;
    #pragma unroll
    for (int k = 0; k < 4; ++k) {
        if (base + k < NN) offs[base + k] = o;
        o += v[k];
    }
    if (tid == 255) bsum[b] = s[255];
}

// scanC with internal bsum prefix (scanB fused): block b sums bsum[0..b-1]
__global__ void k_scanC(int* __restrict__ offs, int* __restrict__ curs,
                        const int* __restrict__ bsum) {
    int tid = threadIdx.x, b = blockIdx.x;
    __shared__ int sacc[128];
    if (tid < 128) sacc[tid] = (tid < b) ? bsum[tid] : 0;   // b <= 97 < 128
    __syncthreads();
    for (int d = 64; d > 0; d >>= 1) {
        if (tid < d) sacc[tid] += sacc[tid + d];
        __syncthreads();
    }
    int add = sacc[0];
    int base = b * 1024 + tid * 4;
    #pragma unroll
    for (int k = 0; k < 4; ++k) {
        int i = base + k;
        if (i < NN) { int o = offs[i] + add; offs[i] = o; curs[i] = o; }
    }
}

// perm[pos] = edge id (dst-sorted); fused glo binary search
__global__ void k_scatter(const int* __restrict__ ei, int* __restrict__ curs,
                          int* __restrict__ perm, const int* __restrict__ batch,
                          int* __restrict__ glo) {
    int e = blockIdx.x * blockDim.x + threadIdx.x;
    if (e < NE) {
        int d = ei[NE + e];
        int pos = atomicAdd(&curs[d], 1);
        perm[pos] = e;
    }
    if (e <= NG) {
        int lo = 0, hi = NN;
        while (lo < hi) { int m = (lo + hi) >> 1; if (batch[m] < e) lo = m + 1; else hi = m; }
        glo[e] = lo;
    }
}

// ===================== fallback-only kernels =====================

__global__ void k_deg(const int* __restrict__ ei, float* __restrict__ deg) {
    int e = blockIdx.x * blockDim.x + threadIdx.x;
    if (e < NE) atomicAdd(&deg[ei[e]], 1.0f);
}

template <int CI, int CO>
__global__ void k_nodeadd(const float* __restrict__ xin, const float* __restrict__ Wr,
                          const float* __restrict__ b, float* __restrict__ outp) {
    constexpr int NPW = 64 / CO;
    const int lane = threadIdx.x & 63;
    const int c = lane % CO;
    const int sub = lane / CO;
    float w[CI];
    #pragma unroll
    for (int i = 0; i < CI; ++i) w[i] = Wr[c * CI + i];
    float bias = b[c];
    int gw = (blockIdx.x * blockDim.x + threadIdx.x) >> 6;
    int nw = (gridDim.x * blockDim.x) >> 6;
    for (int n0 = gw * NPW; n0 < NN; n0 += nw * NPW) {
        int n = n0 + sub;
        if (n < NN) {
            const float* xp = xin + (long)n * CI;
            float acc = outp[(long)n * CO + c] + bias;
            #pragma unroll
            for (int i = 0; i < CI; ++i) acc += xp[i] * w[i];
            outp[(long)n * CO + c] = acc;
        }
    }
}

__global__ void k_pool_at(const float* __restrict__ out2, const int* __restrict__ batch,
                          const float* __restrict__ scale, const float* __restrict__ shift,
                          float* __restrict__ gsum) {
    long t = (long)blockIdx.x * blockDim.x + threadIdx.x;
    int c = (int)(t & 63);
    long n0 = (t >> 6) * 4;
    if (n0 >= NN) return;
    float sc = scale[c], sh = shift[c];
    float acc = 0.f;
    int gprev = batch[n0];
    #pragma unroll
    for (int k = 0; k < 4; ++k) {
        long n = n0 + k;
        if (n >= NN) break;
        int g = batch[n];
        float v = out2[n * 64 + c] * sc + sh;
        v = v > 0.f ? v : 0.f;
        if (g != gprev) {
            atomicAdd(&gsum[(long)gprev * 64 + c], acc);
            acc = 0.f; gprev = g;
        }
        acc += v;
    }
    atomicAdd(&gsum[(long)gprev * 64 + c], acc);
}

__global__ void k_cnt(const int* __restrict__ batch, float* __restrict__ gcnt) {
    int n = blockIdx.x * blockDim.x + threadIdx.x;
    if (n < NN) atomicAdd(&gcnt[batch[n]], 1.0f);
}

__global__ void k_div(float* __restrict__ gsum, const float* __restrict__ gcnt) {
    long t = (long)blockIdx.x * blockDim.x + threadIdx.x;
    if (t < 64L * NG) {
        float cnt = gcnt[t >> 6];
        gsum[t] = gsum[t] / (cnt > 1.f ? cnt : 1.f);
    }
}

// ===================== host =====================

extern "C" void kernel_launch(void* const* d_in, const int* in_sizes, int n_in,
                              void* d_out, int out_size, void* d_ws, size_t ws_size,
                              hipStream_t stream) {
    const float* x   = (const float*)d_in[0];
    const int*   ei  = (const int*)d_in[1];
    const float* ea  = (const float*)d_in[2];
    const int*   bat = (const int*)d_in[3];
    const float* We1 = (const float*)d_in[4];
    const float* b1  = (const float*)d_in[5];
    const float* Wr1 = (const float*)d_in[6];
    const float* g1  = (const float*)d_in[7];
    const float* be1 = (const float*)d_in[8];
    const float* We2 = (const float*)d_in[9];
    const float* b2  = (const float*)d_in[10];
    const float* Wr2 = (const float*)d_in[11];
    const float* g2  = (const float*)d_in[12];
    const float* be2 = (const float*)d_in[13];
    const float* Wf1 = (const float*)d_in[14];
    const float* bf1 = (const float*)d_in[15];
    const float* Wf2 = (const float*)d_in[16];
    const float* bf2 = (const float*)d_in[17];
    float* out = (float*)d_out;
    float* ws  = (float*)d_ws;
    int*   wsi = (int*)d_ws;

    if (ws_size >= (size_t)TOTAL_FAST * sizeof(float)) {
        float* nrm    = ws + FZ_NRM;
        float* st     = ws + FZ_STAT;
        int*   dcnt   = wsi + FZ_DCNT;
        int*   offs   = wsi + O_OFFS;
        int*   curs   = wsi + O_CURS;
        int*   perm   = wsi + O_PERM;
        int*   glo    = wsi + O_GLO;
        int*   bsum   = wsi + O_BSUM;
        float* pooled = ws + O_POOL;
        float* h1     = ws + O_H1;
        float* out2   = ws + O_OUT2;
        unsigned short* msg1 = (unsigned short*)(ws + O_OUT2);  // disjoint lifetime
        unsigned short* msg2 = (unsigned short*)(ws + O_MSG2);
        unsigned short* h1b  = (unsigned short*)(ws + O_H1B);
        float* sums1 = st;        float* ssq1 = st + 32;
        float* sums2 = st + 64;   float* ssq2 = st + 128;

        hipMemsetAsync(d_ws, 0, (size_t)ZN_FAST * sizeof(float), stream);

        k_degcnt<<<(NE + 255) / 256, 256, 0, stream>>>(ei, nrm, dcnt);
        k_scanA<<<NBLK, 256, 0, stream>>>(dcnt, offs, bsum, nrm);
        k_scanC<<<NBLK, 256, 0, stream>>>(offs, curs, bsum);
        k_scatter<<<(NE + 255) / 256, 256, 0, stream>>>(ei, curs, perm, bat, glo);

        // ---- layer 1 ----
        k_edge_lds<16, 32, false><<<2048, 128, 0, stream>>>(
            ei, ea, x, We1, nrm, msg1);
        k_msum<32><<<3125, 256, 0, stream>>>(msg1, offs, dcnt, perm, h1);
        k_root<16, 32, false><<<512, 256, 0, stream>>>(
            x, Wr1, b1, h1, sums1, ssq1);
        // h1 -> h1b (bf16, BN+relu folded; fin fused)
        k_h1b<<<(int)((32L * NN / 8 + 255) / 256), 256, 0, stream>>>(
            h1, sums1, ssq1, g1, be1, h1b);

        // ---- layer 2 (inputs pre-normalized bf16) ----
        k_edge_lds<32, 64, true><<<2048, 256, 0, stream>>>(
            ei, ea, h1b, We2, nrm, msg2);
        k_msum<64><<<6250, 256, 0, stream>>>(msg2, offs, dcnt, perm, out2);
        k_root<32, 64, true><<<512, 256, 0, stream>>>(
            h1b, Wr2, b2, out2, sums2, ssq2);

        // pool (fin2 fused) + fused FC
        k_poolg<<<1250, 256, 0, stream>>>(out2, glo, sums2, ssq2, g2, be2, pooled);
        k_fcfused<<<(NG + 15) / 16, 256, 0, stream>>>(pooled, Wf1, bf1, Wf2, bf2, out);
    } else {
        float* nrm   = ws + B_NORM;
        float* agg1  = ws + B_AGG1;
        float* agg2  = ws + B_AGG2;
        float* gsum  = ws + B_GSUM;
        float* gcnt  = ws + B_GCNT;
        float* st    = ws + B_STAT;
        float* sums1 = st;        float* ssq1 = st + 32;
        float* sums2 = st + 64;   float* ssq2 = st + 128;
        float* sc1   = st + 192;  float* sh1  = st + 224;
        float* sc2   = st + 256;  float* sh2  = st + 320;

        hipMemsetAsync(d_ws, 0, (size_t)ZERO_FB * sizeof(float), stream);

        k_deg<<<(NE + 255) / 256, 256, 0, stream>>>(ei, nrm);
        k_norm<<<(NN + 255) / 256, 256, 0, stream>>>(nrm);

        k_edge_mfma_at<4, 32><<<6250, 256, 0, stream>>>(ei, ea, x, We1, nrm, agg1);
        k_nodeadd<16, 32><<<1024, 256, 0, stream>>>(x, Wr1, b1, agg1);
        k_colstats<32><<<1024, 256, 0, stream>>>(agg1, sums1, ssq1);
        k_fin<<<1, 64, 0, stream>>>(32, sums1, ssq1, g1, be1, sc1, sh1);
        k_bnrelu32<<<(int)((32L * NN + 255) / 256), 256, 0, stream>>>(agg1, sc1, sh1, agg1);

        k_edge_mfma_at<8, 64><<<12500, 256, 0, stream>>>(ei, ea, agg1, We2, nrm, agg2);
        k_nodeadd<32, 64><<<1024, 256, 0, stream>>>(agg1, Wr2, b2, agg2);
        k_colstats<64><<<1024, 256, 0, stream>>>(agg2, sums2, ssq2);
        k_fin<<<1, 64, 0, stream>>>(64, sums2, ssq2, g2, be2, sc2, sh2);

        k_pool_at<<<6250, 256, 0, stream>>>(agg2, bat, sc2, sh2, gsum);
        k_cnt<<<(NN + 255) / 256, 256, 0, stream>>>(bat, gcnt);
        k_div<<<(int)((64L * NG + 255) / 256), 256, 0, stream>>>(gsum, gcnt);
        k_fc<<<1250, 256, 0, stream>>>(gsum, Wf1, bf1, Wf2, bf2, out);
    }
}